// Round 2
// baseline (3047.276 us; speedup 1.0000x reference)
//
#include <hip/hip_runtime.h>
#include <math.h>

#define Bn 64
#define Tn 291
#define Dn 300
#define Hn 10
#define Mn (Bn*Tn)   // 18624

static __device__ __forceinline__ float leaky(float x){ return x >= 0.f ? x : 0.01f*x; }

template<int NT>
static __device__ __forceinline__ float blockSum(float v, float* red){
  __syncthreads();
  int lane = threadIdx.x & 63, wid = threadIdx.x >> 6;
  #pragma unroll
  for (int o = 32; o > 0; o >>= 1) v += __shfl_down(v, o, 64);
  if (lane == 0) red[wid] = v;
  __syncthreads();
  if (threadIdx.x == 0) {
    float s = red[0];
    #pragma unroll
    for (int w = 1; w < NT/64; ++w) s += red[w];
    red[0] = s;
  }
  __syncthreads();
  return red[0];
}

template<int NT>
static __device__ __forceinline__ float blockMax(float v, float* red){
  __syncthreads();
  int lane = threadIdx.x & 63, wid = threadIdx.x >> 6;
  #pragma unroll
  for (int o = 32; o > 0; o >>= 1) v = fmaxf(v, __shfl_down(v, o, 64));
  if (lane == 0) red[wid] = v;
  __syncthreads();
  if (threadIdx.x == 0) {
    float s = red[0];
    #pragma unroll
    for (int w = 1; w < NT/64; ++w) s = fmaxf(s, red[w]);
    red[0] = s;
  }
  __syncthreads();
  return red[0];
}

// ---- image branch: y = leaky(x2 @ Wimg.T + bimg); lnP = LN_300(y)*g2+be2 ----
__global__ __launch_bounds__(256)
void k_img_lnp(const float* __restrict__ x2, const float* __restrict__ Wimg,
               const float* __restrict__ bimg, const float* __restrict__ g2,
               const float* __restrict__ be2, float* __restrict__ lnP)
{
  int b = blockIdx.x, tid = threadIdx.x;
  __shared__ float sx[1000];
  __shared__ float sy[300];
  __shared__ float red[4];
  for (int i = tid; i < 1000; i += 256) sx[i] = x2[b*1000 + i];
  __syncthreads();
  for (int j = tid; j < 300; j += 256) {
    const float* w = Wimg + j*1000;
    float a = 0.f;
    for (int i = 0; i < 1000; ++i) a += sx[i]*w[i];
    sy[j] = leaky(a + bimg[j]);
  }
  __syncthreads();
  float s = 0.f, ss = 0.f;
  for (int j = tid; j < 300; j += 256) { float v = sy[j]; s += v; ss += v*v; }
  float tot  = blockSum<256>(s, red);
  float tot2 = blockSum<256>(ss, red);
  float mu   = tot * (1.f/300.f);
  float var  = tot2 * (1.f/300.f) - mu*mu;
  float rstd = rsqrtf(var + 1e-5f);
  for (int j = tid; j < 300; j += 256)
    lnP[b*300 + j] = (sy[j]-mu)*rstd*g2[j] + be2[j];
}

// ---- lnT: LayerNorm over (291,300) per batch sample ----
__global__ __launch_bounds__(1024)
void k_lnT(const float* __restrict__ x1, const float* __restrict__ g1,
           const float* __restrict__ be1, float* __restrict__ out)
{
  int b = blockIdx.x, tid = threadIdx.x;
  __shared__ float red[16];
  const float4* xb = (const float4*)(x1 + (size_t)b*87300);
  const float4* g4 = (const float4*)g1;
  const float4* b4 = (const float4*)be1;
  float4* o4 = (float4*)(out + (size_t)b*87300);
  float s = 0.f, ss = 0.f;
  for (int i = tid; i < 21825; i += 1024) {
    float4 v = xb[i];
    s  += v.x+v.y+v.z+v.w;
    ss += v.x*v.x+v.y*v.y+v.z*v.z+v.w*v.w;
  }
  float tot  = blockSum<1024>(s, red);
  float tot2 = blockSum<1024>(ss, red);
  float mu   = tot / 87300.f;
  float var  = tot2 / 87300.f - mu*mu;
  float rstd = rsqrtf(var + 1e-5f);
  for (int i = tid; i < 21825; i += 1024) {
    float4 v = xb[i], g = g4[i], be = b4[i], o;
    o.x = (v.x-mu)*rstd*g.x + be.x;
    o.y = (v.y-mu)*rstd*g.y + be.y;
    o.z = (v.z-mu)*rstd*g.z + be.z;
    o.w = (v.w-mu)*rstd*g.w + be.w;
    o4[i] = o;
  }
}

// ---- T->P cross attention (single query) + v for P->T branch ----
__global__ __launch_bounds__(320)
void k_tp(const float* __restrict__ lnP, const float* __restrict__ lnT,
          const float* __restrict__ Wq, const float* __restrict__ Wk,
          const float* __restrict__ Wv, const float* __restrict__ Wvpt,
          float* __restrict__ RTP, float* __restrict__ vpt)
{
  int b = blockIdx.x, tid = threadIdx.x;
  __shared__ float sP[300], sQ[300], sM[300], sA[291], sW[300], red[5];
  if (tid < 300) sP[tid] = lnP[b*300 + tid];
  __syncthreads();
  if (tid < 300) {
    const float* w = Wq + tid*300;
    float a = 0.f;
    for (int i = 0; i < 300; ++i) a += sP[i]*w[i];
    sQ[tid] = a;
  }
  __syncthreads();
  if (tid < 300) {   // m = Wk.T @ q
    float a = 0.f;
    for (int j = 0; j < 300; ++j) a += sQ[j]*Wk[j*300 + tid];
    sM[tid] = a;
  }
  __syncthreads();
  float sc = -1e30f;
  if (tid < 291) {
    const float* r = lnT + ((size_t)b*Tn + tid)*300;
    float a = 0.f;
    for (int i = 0; i < 300; ++i) a += r[i]*sM[i];
    sc = a;
  }
  float mx  = blockMax<320>(sc, red);
  float e   = (tid < 291) ? __expf(sc - mx) : 0.f;
  float den = blockSum<320>(e, red);
  if (tid < 291) sA[tid] = e;
  __syncthreads();
  if (tid < 300) {
    float a = 0.f;
    for (int t = 0; t < 291; ++t) a += sA[t]*lnT[((size_t)b*Tn + t)*300 + tid];
    sW[tid] = a / den;
  }
  __syncthreads();
  if (tid < 300) {
    const float* w = Wv + tid*300;
    float a = 0.f;
    for (int i = 0; i < 300; ++i) a += sW[i]*w[i];
    RTP[b*300 + tid] = a + sP[tid];
    const float* w2 = Wvpt + tid*300;
    float a2 = 0.f;
    for (int i = 0; i < 300; ++i) a2 += sP[i]*w2[i];
    vpt[b*300 + tid] = a2;
  }
}

// ---- rpt = lnT + vpt (broadcast over t) ----
__global__ __launch_bounds__(256)
void k_rpt(const float* __restrict__ lnT, const float* __restrict__ vpt,
           float* __restrict__ rpt)
{
  int idx = blockIdx.x*256 + threadIdx.x;
  if (idx >= Mn*Dn/4) return;
  int row = idx / 75;
  int c4  = idx % 75;
  int b   = row / Tn;
  float4 v = ((const float4*)vpt)[b*75 + c4];
  float4 x = ((const float4*)lnT)[idx];
  float4 o; o.x = x.x+v.x; o.y = x.y+v.y; o.z = x.z+v.z; o.w = x.w+v.w;
  ((float4*)rpt)[idx] = o;
}

// ---- pack conv weights: Wp[c][r][300] ----
__global__ __launch_bounds__(256)
void k_pack(const float* __restrict__ Wc1, const float* __restrict__ Wc2,
            const float* __restrict__ Wc3, const float* __restrict__ Wc4,
            float* __restrict__ Wp)
{
  int idx = blockIdx.x*256 + threadIdx.x;
  if (idx >= 2*250*300) return;
  int d  = idx % 300;
  int rc = idx / 300;
  int c  = rc / 250;
  int r  = rc % 250;
  const float* W; int kh, ro;
  if      (r < 25)  { W = Wc1; kh = 1; ro = r;      }
  else if (r < 75)  { W = Wc2; kh = 2; ro = r - 25; }
  else if (r < 150) { W = Wc3; kh = 3; ro = r - 75; }
  else              { W = Wc4; kh = 4; ro = r - 150;}
  int o = ro / kh, dh = ro % kh;
  Wp[idx] = W[((o*2 + c)*kh + dh)*300 + d];
}

// ---- GEMM v2: 128x64 tile, 8x4 micro-tile. C[m,n] = sum_k A[m,k]*W[n,k] ----
#define G2BM 128
#define G2BN 64
#define G2BK 20
__global__ __launch_bounds__(256)
void k_gemm2(const float* __restrict__ A0, const float* __restrict__ A1, const float* __restrict__ A2,
             const float* __restrict__ W0, const float* __restrict__ W1, const float* __restrict__ W2,
             float* __restrict__ C0, float* __restrict__ C1, float* __restrict__ C2,
             int N)
{
  const float* A = (blockIdx.z == 0) ? A0 : (blockIdx.z == 1) ? A1 : A2;
  const float* W = (blockIdx.z == 0) ? W0 : (blockIdx.z == 1) ? W1 : W2;
  float*       C = (blockIdx.z == 0) ? C0 : (blockIdx.z == 1) ? C1 : C2;
  int m0 = blockIdx.x*G2BM, n0 = blockIdx.y*G2BN;
  __shared__ float As[G2BK][G2BM+4];
  __shared__ float Bs[G2BK][G2BN+4];
  int tid = threadIdx.x;
  int tm = tid >> 4, tn = tid & 15;      // 16x16 threads -> 8 rows x 4 cols each
  float acc[8][4] = {};
  for (int k0 = 0; k0 < 300; k0 += G2BK) {
    #pragma unroll
    for (int u = 0; u < 10; ++u) {
      int i = tid + u*256;
      int r = i / G2BK, c = i % G2BK;
      int m = m0 + r;
      As[c][r] = (m < Mn) ? A[(size_t)m*300 + k0 + c] : 0.f;
    }
    #pragma unroll
    for (int u = 0; u < 5; ++u) {
      int i = tid + u*256;
      int r = i / G2BK, c = i % G2BK;
      int n = n0 + r;
      Bs[c][r] = (n < N) ? W[(size_t)n*300 + k0 + c] : 0.f;
    }
    __syncthreads();
    #pragma unroll
    for (int kk = 0; kk < G2BK; ++kk) {
      float4 a0 = *reinterpret_cast<const float4*>(&As[kk][tm*8]);
      float4 a1 = *reinterpret_cast<const float4*>(&As[kk][tm*8+4]);
      float4 bv = *reinterpret_cast<const float4*>(&Bs[kk][tn*4]);
      float am[8] = {a0.x,a0.y,a0.z,a0.w,a1.x,a1.y,a1.z,a1.w};
      float bb[4] = {bv.x,bv.y,bv.z,bv.w};
      #pragma unroll
      for (int i = 0; i < 8; ++i)
        #pragma unroll
        for (int j = 0; j < 4; ++j)
          acc[i][j] += am[i]*bb[j];
    }
    __syncthreads();
  }
  #pragma unroll
  for (int i = 0; i < 8; ++i) {
    int m = m0 + tm*8 + i;
    if (m < Mn) {
      #pragma unroll
      for (int j = 0; j < 4; ++j) {
        int n = n0 + tn*4 + j;
        if (n < N) C[(size_t)m*N + n] = acc[i][j];
      }
    }
  }
}

// ---- attention v2: j-parallel (8 lanes/row), no-max softmax, swizzled LDS ----
__global__ __launch_bounds__(256)
void k_attn2(const float* __restrict__ Q, const float* __restrict__ Kb,
             const float* __restrict__ Vb, float* __restrict__ O)
{
  int b = blockIdx.x, h = blockIdx.y, tid = threadIdx.x;
  __shared__ float Ks[Tn][32];
  __shared__ float Vs[Tn][32];
  const size_t base = (size_t)b*Tn*300 + h*30;
  // stage with xor swizzle: element (t,k) stored at slot ((k>>2)^(t&7))*4 | (k&3)
  for (int i = tid; i < Tn*32; i += 256) {
    int t = i >> 5, k = i & 31;
    float kv = 0.f, vv = 0.f;
    if (k < 30) {
      kv = Kb[base + (size_t)t*300 + k];
      vv = Vb[base + (size_t)t*300 + k];
    }
    int ss = (((k>>2) ^ (t&7))<<2) | (k&3);
    Ks[t][ss] = kv; Vs[t][ss] = vv;
  }
  __syncthreads();
  int lane = tid & 63;
  int w  = tid >> 6;       // wave 0..3
  int rg = lane >> 3;      // row-in-wave 0..7
  int jl = lane & 7;       // j-lane 0..7
  const float scale = 0.31622776601683794f;  // 1/sqrt(H)
  #pragma unroll 1
  for (int pass = 0; pass < 10; ++pass) {
    int row = pass*32 + w*8 + rg;
    bool valid = row < Tn;
    float q[32];
    if (valid) {
      const float2* qp = (const float2*)(Q + base + (size_t)row*300);
      #pragma unroll
      for (int k2 = 0; k2 < 15; ++k2) { float2 v = qp[k2]; q[k2*2] = v.x; q[k2*2+1] = v.y; }
    } else {
      #pragma unroll
      for (int k = 0; k < 30; ++k) q[k] = 0.f;
    }
    q[30] = 0.f; q[31] = 0.f;
    float l = 0.f, acc[32];
    #pragma unroll
    for (int k = 0; k < 32; ++k) acc[k] = 0.f;
    for (int j = jl; j < Tn; j += 8) {
      int sw = (j & 7) << 2;
      float s0 = 0.f, s1 = 0.f, s2 = 0.f, s3 = 0.f;
      #pragma unroll
      for (int oc = 0; oc < 8; ++oc) {
        const float4 kv = *reinterpret_cast<const float4*>(&Ks[j][(oc<<2) ^ sw]);
        s0 += q[oc*4+0]*kv.x; s1 += q[oc*4+1]*kv.y;
        s2 += q[oc*4+2]*kv.z; s3 += q[oc*4+3]*kv.w;
      }
      float p = __expf(((s0+s1)+(s2+s3))*scale);
      l += p;
      #pragma unroll
      for (int oc = 0; oc < 8; ++oc) {
        const float4 vv = *reinterpret_cast<const float4*>(&Vs[j][(oc<<2) ^ sw]);
        acc[oc*4+0] += p*vv.x; acc[oc*4+1] += p*vv.y;
        acc[oc*4+2] += p*vv.z; acc[oc*4+3] += p*vv.w;
      }
    }
    // merge partial (l, acc) across the 8 j-lanes
    #pragma unroll
    for (int mask = 1; mask <= 4; mask <<= 1) {
      l += __shfl_xor(l, mask, 64);
      #pragma unroll
      for (int k = 0; k < 30; ++k) acc[k] += __shfl_xor(acc[k], mask, 64);
    }
    if (valid && jl == 0) {
      float inv = 1.f/l;
      float* op = O + base + (size_t)row*300;
      #pragma unroll
      for (int k = 0; k < 30; ++k) op[k] = acc[k]*inv;
    }
  }
}

// ---- conv head reduce v2: LDS-staged (G0+G1) column slice, per-(b,head) ----
__global__ __launch_bounds__(256)
void k_convred2(const float* __restrict__ G0, const float* __restrict__ G1,
                const float* __restrict__ bc1, const float* __restrict__ bc2,
                const float* __restrict__ bc3, const float* __restrict__ bc4,
                float* __restrict__ out100)
{
  int b = blockIdx.x, head = blockIdx.y;
  int kh  = head + 1;
  int off = (head == 0) ? 0 : (head == 1) ? 25 : (head == 2) ? 75 : 150;
  const float* bc = (head == 0) ? bc1 : (head == 1) ? bc2 : (head == 2) ? bc3 : bc4;
  int ncol = 25*kh;
  int ncp  = ncol | 1;            // odd stride -> conflict-free strided reads
  int L = Tn - kh + 1;
  __shared__ float S[67*101];
  int tid = threadIdx.x, lane = tid & 63;
  float mx[7];
  #pragma unroll
  for (int u = 0; u < 7; ++u) mx[u] = -1e30f;
  for (int l0 = 0; l0 < L; l0 += 64) {
    int nrows = min(64 + kh - 1, Tn - l0);
    __syncthreads();
    for (int i = tid; i < nrows*ncol; i += 256) {
      int r = i / ncol, c = i % ncol;
      size_t g = (size_t)(b*Tn + l0 + r)*250 + off + c;
      S[r*ncp + c] = G0[g] + G1[g];
    }
    __syncthreads();
    int lmax = min(64, L - l0);
    #pragma unroll
    for (int u = 0; u < 7; ++u) {
      int o = (tid >> 6) + u*4;
      int dl = lane;
      if (o < 25 && dl < lmax) {
        float s = bc[o];
        for (int dh = 0; dh < kh; ++dh)
          s += S[(dl+dh)*ncp + o*kh + dh];
        mx[u] = fmaxf(mx[u], leaky(s));
      }
    }
  }
  #pragma unroll
  for (int u = 0; u < 7; ++u) {
    float v = mx[u];
    #pragma unroll
    for (int ofs = 32; ofs > 0; ofs >>= 1) v = fmaxf(v, __shfl_down(v, ofs, 64));
    int o = (tid >> 6) + u*4;
    if (lane == 0 && o < 25)
      out100[b*100 + head*25 + o] = v;
  }
}

// ---- final head ----
__global__ __launch_bounds__(320)
void k_final(const float* __restrict__ RTP, const float* __restrict__ out100,
             const float* __restrict__ Wlin, const float* __restrict__ blin,
             const float* __restrict__ Wlast, const float* __restrict__ blast,
             float* __restrict__ Y)
{
  int b = blockIdx.x, tid = threadIdx.x;
  __shared__ float cat[600];
  __shared__ float s100[100];
  __shared__ float red[5];
  if (tid < 100) s100[tid] = out100[b*100 + tid];
  if (tid < 300) cat[tid] = RTP[b*300 + tid];
  __syncthreads();
  if (tid < 300) {
    const float* w = Wlin + tid*100;
    float a = blin[tid];
    for (int j = 0; j < 100; ++j) a += s100[j]*w[j];
    cat[300 + tid] = leaky(a);
  }
  __syncthreads();
  for (int c = 0; c < 2; ++c) {
    float a = 0.f;
    for (int i = tid; i < 600; i += 320) a += cat[i]*Wlast[c*600 + i];
    a = blockSum<320>(a, red);
    if (tid == 0) Y[b*2 + c] = a + blast[c];
  }
}

extern "C" void kernel_launch(void* const* d_in, const int* in_sizes, int n_in,
                              void* d_out, int out_size, void* d_ws, size_t ws_size,
                              hipStream_t stream)
{
  (void)in_sizes; (void)n_in; (void)out_size; (void)ws_size;
  const float* x1    = (const float*)d_in[0];
  const float* x2    = (const float*)d_in[1];
  const float* Wimg  = (const float*)d_in[2];
  const float* bimg  = (const float*)d_in[3];
  const float* g1    = (const float*)d_in[4];
  const float* be1   = (const float*)d_in[5];
  const float* g2    = (const float*)d_in[6];
  const float* be2   = (const float*)d_in[7];
  const float* Wq_tp = (const float*)d_in[8];
  const float* Wk_tp = (const float*)d_in[9];
  const float* Wv_tp = (const float*)d_in[10];
  const float* Wv_pt = (const float*)d_in[13];
  const float* Wq1 = (const float*)d_in[14];
  const float* Wk1 = (const float*)d_in[15];
  const float* Wv1 = (const float*)d_in[16];
  const float* Wm1 = (const float*)d_in[17];
  const float* Wq2 = (const float*)d_in[18];
  const float* Wk2 = (const float*)d_in[19];
  const float* Wv2 = (const float*)d_in[20];
  const float* Wm2 = (const float*)d_in[21];
  const float* Wq3 = (const float*)d_in[22];
  const float* Wk3 = (const float*)d_in[23];
  const float* Wv3 = (const float*)d_in[24];
  const float* Wm3 = (const float*)d_in[25];
  const float* Wc1 = (const float*)d_in[26];
  const float* Wc2 = (const float*)d_in[27];
  const float* Wc3 = (const float*)d_in[28];
  const float* Wc4 = (const float*)d_in[29];
  const float* bc1 = (const float*)d_in[30];
  const float* bc2 = (const float*)d_in[31];
  const float* bc3 = (const float*)d_in[32];
  const float* bc4 = (const float*)d_in[33];
  const float* Wlin  = (const float*)d_in[34];
  const float* blin  = (const float*)d_in[35];
  const float* Wlast = (const float*)d_in[36];
  const float* blast = (const float*)d_in[37];

  float* ws     = (float*)d_ws;
  float* lnP    = ws;
  float* RTP    = ws + 19200;
  float* vpt    = ws + 38400;
  float* out100 = ws + 57600;
  float* Wp     = ws + 64000;
  const size_t BS = (size_t)Mn*Dn;
  float* buf0 = ws + 262144;
  float* buf1 = buf0 + BS;
  float* buf2 = buf1 + BS;
  float* buf3 = buf2 + BS;
  float* buf4 = buf3 + BS;

  k_img_lnp<<<Bn, 256, 0, stream>>>(x2, Wimg, bimg, g2, be2, lnP);
  k_lnT<<<Bn, 1024, 0, stream>>>(x1, g1, be1, buf0);                 // buf0 = lnT
  k_tp<<<Bn, 320, 0, stream>>>(lnP, buf0, Wq_tp, Wk_tp, Wv_tp, Wv_pt, RTP, vpt);
  k_rpt<<<(Mn*Dn/4 + 255)/256, 256, 0, stream>>>(buf0, vpt, buf1);   // buf1 = R_P_T
  k_pack<<<(2*250*300 + 255)/256, 256, 0, stream>>>(Wc1, Wc2, Wc3, Wc4, Wp);

  dim3 gqkv(146, 5, 3), gone(146, 5, 1), gconv(146, 4, 2), gat(Bn, Hn);
  // MHA1: in=lnT(buf0) -> Q=buf2 K=buf3 V=buf4 ; O=buf0 ; a1=buf2
  k_gemm2<<<gqkv, 256, 0, stream>>>(buf0,buf0,buf0, Wq1,Wk1,Wv1, buf2,buf3,buf4, 300);
  k_attn2<<<gat, 256, 0, stream>>>(buf2, buf3, buf4, buf0);
  k_gemm2<<<gone, 256, 0, stream>>>(buf0,buf0,buf0, Wm1,Wm1,Wm1, buf2,buf2,buf2, 300);
  // MHA2: in=a1(buf2) -> Q=buf0 K=buf3 V=buf4 ; O=buf2 ; a2=buf0
  k_gemm2<<<gqkv, 256, 0, stream>>>(buf2,buf2,buf2, Wq2,Wk2,Wv2, buf0,buf3,buf4, 300);
  k_attn2<<<gat, 256, 0, stream>>>(buf0, buf3, buf4, buf2);
  k_gemm2<<<gone, 256, 0, stream>>>(buf2,buf2,buf2, Wm2,Wm2,Wm2, buf0,buf0,buf0, 300);
  // MHA3: in=a2(buf0) -> Q=buf2 K=buf3 V=buf4 ; O=buf0 ; a3=buf2
  k_gemm2<<<gqkv, 256, 0, stream>>>(buf0,buf0,buf0, Wq3,Wk3,Wv3, buf2,buf3,buf4, 300);
  k_attn2<<<gat, 256, 0, stream>>>(buf2, buf3, buf4, buf0);
  k_gemm2<<<gone, 256, 0, stream>>>(buf0,buf0,buf0, Wm3,Wm3,Wm3, buf2,buf2,buf2, 300);
  // conv GEMMs
  k_gemm2<<<gconv, 256, 0, stream>>>(buf1,buf2,buf1, Wp,Wp+75000,Wp, buf3,buf4,buf3, 250);
  k_convred2<<<dim3(Bn,4), 256, 0, stream>>>(buf3, buf4, bc1, bc2, bc3, bc4, out100);
  k_final<<<Bn, 320, 0, stream>>>(RTP, out100, Wlin, blin, Wlast, blast, (float*)d_out);
}

// Round 3
// 1414.563 us; speedup vs baseline: 2.1542x; 2.1542x over previous
//
#include <hip/hip_runtime.h>
#include <hip/hip_bf16.h>
#include <math.h>

#define Bn 64
#define Tn 291
#define Dn 300
#define Hn 10
#define Mn (Bn*Tn)   // 18624
#define Mp 18688     // 146*128 padded rows
#define Kp 320       // padded K / activation pitch

typedef __bf16 bf16x8 __attribute__((ext_vector_type(8)));
typedef float f32x4 __attribute__((ext_vector_type(4)));

static __device__ __forceinline__ float leaky(float x){ return x >= 0.f ? x : 0.01f*x; }

template<int NT>
static __device__ __forceinline__ float blockSum(float v, float* red){
  __syncthreads();
  int lane = threadIdx.x & 63, wid = threadIdx.x >> 6;
  #pragma unroll
  for (int o = 32; o > 0; o >>= 1) v += __shfl_down(v, o, 64);
  if (lane == 0) red[wid] = v;
  __syncthreads();
  if (threadIdx.x == 0) {
    float s = red[0];
    #pragma unroll
    for (int w = 1; w < NT/64; ++w) s += red[w];
    red[0] = s;
  }
  __syncthreads();
  return red[0];
}

template<int NT>
static __device__ __forceinline__ float blockMax(float v, float* red){
  __syncthreads();
  int lane = threadIdx.x & 63, wid = threadIdx.x >> 6;
  #pragma unroll
  for (int o = 32; o > 0; o >>= 1) v = fmaxf(v, __shfl_down(v, o, 64));
  if (lane == 0) red[wid] = v;
  __syncthreads();
  if (threadIdx.x == 0) {
    float s = red[0];
    #pragma unroll
    for (int w = 1; w < NT/64; ++w) s = fmaxf(s, red[w]);
    red[0] = s;
  }
  __syncthreads();
  return red[0];
}

// ---- image branch ----
__global__ __launch_bounds__(256)
void k_img_lnp(const float* __restrict__ x2, const float* __restrict__ Wimg,
               const float* __restrict__ bimg, const float* __restrict__ g2,
               const float* __restrict__ be2, float* __restrict__ lnP)
{
  int b = blockIdx.x, tid = threadIdx.x;
  __shared__ float sx[1000];
  __shared__ float sy[300];
  __shared__ float red[4];
  for (int i = tid; i < 1000; i += 256) sx[i] = x2[b*1000 + i];
  __syncthreads();
  for (int j = tid; j < 300; j += 256) {
    const float* w = Wimg + j*1000;
    float a = 0.f;
    for (int i = 0; i < 1000; ++i) a += sx[i]*w[i];
    sy[j] = leaky(a + bimg[j]);
  }
  __syncthreads();
  float s = 0.f, ss = 0.f;
  for (int j = tid; j < 300; j += 256) { float v = sy[j]; s += v; ss += v*v; }
  float tot  = blockSum<256>(s, red);
  float tot2 = blockSum<256>(ss, red);
  float mu   = tot * (1.f/300.f);
  float var  = tot2 * (1.f/300.f) - mu*mu;
  float rstd = rsqrtf(var + 1e-5f);
  for (int j = tid; j < 300; j += 256)
    lnP[b*300 + j] = (sy[j]-mu)*rstd*g2[j] + be2[j];
}

// ---- lnT: LayerNorm over (291,300); writes fp32 (pitch 300) + bf16 (pitch 320, zero-padded) ----
__global__ __launch_bounds__(1024)
void k_lnT(const float* __restrict__ x1, const float* __restrict__ g1,
           const float* __restrict__ be1, float* __restrict__ outf,
           __hip_bfloat16* __restrict__ outb)
{
  int b = blockIdx.x, tid = threadIdx.x;
  __shared__ float red[16];
  const float4* xb = (const float4*)(x1 + (size_t)b*87300);
  const float4* g4 = (const float4*)g1;
  const float4* b4 = (const float4*)be1;
  float4* o4 = (float4*)(outf + (size_t)b*87300);
  float s = 0.f, ss = 0.f;
  for (int i = tid; i < 21825; i += 1024) {
    float4 v = xb[i];
    s  += v.x+v.y+v.z+v.w;
    ss += v.x*v.x+v.y*v.y+v.z*v.z+v.w*v.w;
  }
  float tot  = blockSum<1024>(s, red);
  float tot2 = blockSum<1024>(ss, red);
  float mu   = tot / 87300.f;
  float var  = tot2 / 87300.f - mu*mu;
  float rstd = rsqrtf(var + 1e-5f);
  for (int i = tid; i < 21825; i += 1024) {
    float4 v = xb[i], g = g4[i], be = b4[i], o;
    o.x = (v.x-mu)*rstd*g.x + be.x;
    o.y = (v.y-mu)*rstd*g.y + be.y;
    o.z = (v.z-mu)*rstd*g.z + be.z;
    o.w = (v.w-mu)*rstd*g.w + be.w;
    o4[i] = o;
  }
  const float* xs = x1 + (size_t)b*87300;
  for (int e = tid; e < Tn*Dn; e += 1024) {
    int t = e/300;
    float x = xs[e];
    outb[(size_t)(b*Tn+t)*Kp + (e - t*300)] = __float2bfloat16((x-mu)*rstd*g1[e] + be1[e]);
  }
  for (int e = tid; e < Tn*20; e += 1024) {
    int t = e/20, d = 300 + e%20;
    outb[(size_t)(b*Tn+t)*Kp + d] = __float2bfloat16(0.f);
  }
}

// ---- T->P cross attention (single query) + v for P->T branch ----
__global__ __launch_bounds__(320)
void k_tp(const float* __restrict__ lnP, const float* __restrict__ lnT,
          const float* __restrict__ Wq, const float* __restrict__ Wk,
          const float* __restrict__ Wv, const float* __restrict__ Wvpt,
          float* __restrict__ RTP, float* __restrict__ vpt)
{
  int b = blockIdx.x, tid = threadIdx.x;
  __shared__ float sP[300], sQ[300], sM[300], sA[291], sW[300], red[5];
  if (tid < 300) sP[tid] = lnP[b*300 + tid];
  __syncthreads();
  if (tid < 300) {
    const float* w = Wq + tid*300;
    float a = 0.f;
    for (int i = 0; i < 300; ++i) a += sP[i]*w[i];
    sQ[tid] = a;
  }
  __syncthreads();
  if (tid < 300) {
    float a = 0.f;
    for (int j = 0; j < 300; ++j) a += sQ[j]*Wk[j*300 + tid];
    sM[tid] = a;
  }
  __syncthreads();
  float sc = -1e30f;
  if (tid < 291) {
    const float* r = lnT + ((size_t)b*Tn + tid)*300;
    float a = 0.f;
    for (int i = 0; i < 300; ++i) a += r[i]*sM[i];
    sc = a;
  }
  float mx  = blockMax<320>(sc, red);
  float e   = (tid < 291) ? __expf(sc - mx) : 0.f;
  float den = blockSum<320>(e, red);
  if (tid < 291) sA[tid] = e;
  __syncthreads();
  if (tid < 300) {
    float a = 0.f;
    for (int t = 0; t < 291; ++t) a += sA[t]*lnT[((size_t)b*Tn + t)*300 + tid];
    sW[tid] = a / den;
  }
  __syncthreads();
  if (tid < 300) {
    const float* w = Wv + tid*300;
    float a = 0.f;
    for (int i = 0; i < 300; ++i) a += sW[i]*w[i];
    RTP[b*300 + tid] = a + sP[tid];
    const float* w2 = Wvpt + tid*300;
    float a2 = 0.f;
    for (int i = 0; i < 300; ++i) a2 += sP[i]*w2[i];
    vpt[b*300 + tid] = a2;
  }
}

// ---- rpt = lnT + vpt (broadcast over t), bf16 pitch-320 zero-padded ----
__global__ __launch_bounds__(256)
void k_rptb(const float* __restrict__ lnT, const float* __restrict__ vpt,
            __hip_bfloat16* __restrict__ out)
{
  int idx = blockIdx.x*256 + threadIdx.x;
  if (idx >= Mn*Kp) return;
  int m = idx / Kp, d = idx - m*Kp;
  int b = m / Tn;
  float v = (d < 300) ? lnT[(size_t)m*300 + d] + vpt[b*300 + d] : 0.f;
  out[idx] = __float2bfloat16(v);
}

// ---- convert 12 square weights fp32[300][300] -> bf16[320][320] zero-padded ----
struct Wptrs { const float* p[12]; };
__global__ __launch_bounds__(256)
void k_wcvt(Wptrs wp, __hip_bfloat16* __restrict__ out)
{
  int idx = blockIdx.x*256 + threadIdx.x;
  if (idx >= 12*Kp*Kp) return;
  int mat = idx / (Kp*Kp);
  int rem = idx - mat*(Kp*Kp);
  int r = rem / Kp, c = rem - r*Kp;
  float v = (r < 300 && c < 300) ? wp.p[mat][r*300 + c] : 0.f;
  out[idx] = __float2bfloat16(v);
}

// ---- pack conv weights -> bf16 [2][256][320] zero-padded ----
__global__ __launch_bounds__(256)
void k_wpackb(const float* __restrict__ Wc1, const float* __restrict__ Wc2,
              const float* __restrict__ Wc3, const float* __restrict__ Wc4,
              __hip_bfloat16* __restrict__ out)
{
  int idx = blockIdx.x*256 + threadIdx.x;
  if (idx >= 2*256*Kp) return;
  int c  = idx % Kp;
  int rc = idx / Kp;
  int ch = rc / 256;
  int r  = rc % 256;
  float v = 0.f;
  if (r < 250 && c < 300) {
    const float* W; int kh, ro;
    if      (r < 25)  { W = Wc1; kh = 1; ro = r;      }
    else if (r < 75)  { W = Wc2; kh = 2; ro = r - 25; }
    else if (r < 150) { W = Wc3; kh = 3; ro = r - 75; }
    else              { W = Wc4; kh = 4; ro = r - 150;}
    int o = ro/kh, dh = ro%kh;
    v = W[((o*2 + ch)*kh + dh)*300 + c];
  }
  out[idx] = __float2bfloat16(v);
}

// ---- store helper ----
static __device__ __forceinline__ void cvt_store(__hip_bfloat16* p, float v){ *p = __float2bfloat16(v); }
static __device__ __forceinline__ void cvt_store(float* p, float v){ *p = v; }

// ---- bf16 MFMA GEMM: C[m,n] = sum_k A[m,k]*W[n,k]. A:[Mp][320] bf16, W:[pitchN][320] bf16.
//      128x64 tile, 4 waves, K=320 in 5 tiles of 64, double-buffered LDS, XOR swizzle. ----
template<typename OutT>
__global__ __launch_bounds__(256)
void k_mfma(const __hip_bfloat16* __restrict__ A0, const __hip_bfloat16* __restrict__ A1,
            const __hip_bfloat16* __restrict__ A2,
            const __hip_bfloat16* __restrict__ W0, const __hip_bfloat16* __restrict__ W1,
            const __hip_bfloat16* __restrict__ W2,
            OutT* __restrict__ C0, OutT* __restrict__ C1, OutT* __restrict__ C2,
            int pitch)
{
  const ushort* A = (const ushort*)(blockIdx.z==0 ? A0 : blockIdx.z==1 ? A1 : A2);
  const ushort* W = (const ushort*)(blockIdx.z==0 ? W0 : blockIdx.z==1 ? W1 : W2);
  OutT*         C = blockIdx.z==0 ? C0 : blockIdx.z==1 ? C1 : C2;
  int m0 = blockIdx.x*128, n0 = blockIdx.y*64;
  __shared__ alignas(16) ushort As[2][128*64];
  __shared__ alignas(16) ushort Bs[2][64*64];
  int tid = threadIdx.x;
  int lane = tid & 63, w = tid >> 6, wr = w >> 1, wc = w & 1;
  int lm = lane & 15, lk = lane >> 4;
  f32x4 acc[4][2] = {};
  uint4 ra[4], rw[2];

  auto loadregs = [&](int kt){
    #pragma unroll
    for (int u = 0; u < 4; ++u) {
      int s = tid + u*256; int row = s >> 3, kg = s & 7;
      ra[u] = *(const uint4*)(A + (size_t)(m0+row)*Kp + kt*64 + kg*8);
    }
    #pragma unroll
    for (int u = 0; u < 2; ++u) {
      int s = tid + u*256; int row = s >> 3, kg = s & 7;
      rw[u] = *(const uint4*)(W + (size_t)(n0+row)*Kp + kt*64 + kg*8);
    }
  };
  auto writeLDS = [&](int buf){
    #pragma unroll
    for (int u = 0; u < 4; ++u) {
      int s = tid + u*256; int row = s >> 3, kg = s & 7;
      *(uint4*)&As[buf][row*64 + ((kg ^ (row&7)) << 3)] = ra[u];
    }
    #pragma unroll
    for (int u = 0; u < 2; ++u) {
      int s = tid + u*256; int row = s >> 3, kg = s & 7;
      *(uint4*)&Bs[buf][row*64 + ((kg ^ (row&7)) << 3)] = rw[u];
    }
  };
  auto compute = [&](int buf){
    #pragma unroll
    for (int s = 0; s < 2; ++s) {
      bf16x8 af[4], bfr[2];
      int kg = s*4 + lk;
      #pragma unroll
      for (int mf = 0; mf < 4; ++mf) {
        int r = wr*64 + mf*16 + lm;
        af[mf] = *(const bf16x8*)&As[buf][r*64 + ((kg ^ (r&7)) << 3)];
      }
      #pragma unroll
      for (int nf = 0; nf < 2; ++nf) {
        int r = wc*32 + nf*16 + lm;
        bfr[nf] = *(const bf16x8*)&Bs[buf][r*64 + ((kg ^ (r&7)) << 3)];
      }
      #pragma unroll
      for (int mf = 0; mf < 4; ++mf)
        #pragma unroll
        for (int nf = 0; nf < 2; ++nf)
          acc[mf][nf] = __builtin_amdgcn_mfma_f32_16x16x32_bf16(af[mf], bfr[nf], acc[mf][nf], 0, 0, 0);
    }
  };

  loadregs(0); writeLDS(0);
  __syncthreads();
  #pragma unroll 1
  for (int kt = 0; kt < 5; ++kt) {
    if (kt < 4) loadregs(kt+1);
    compute(kt & 1);
    if (kt < 4) {
      __syncthreads();
      writeLDS((kt+1) & 1);
      __syncthreads();
    }
  }
  #pragma unroll
  for (int mf = 0; mf < 4; ++mf) {
    #pragma unroll
    for (int i = 0; i < 4; ++i) {
      int m = m0 + wr*64 + mf*16 + lk*4 + i;
      #pragma unroll
      for (int nf = 0; nf < 2; ++nf) {
        int n = n0 + wc*32 + nf*16 + lm;
        cvt_store(C + (size_t)m*pitch + n, acc[mf][nf][i]);
      }
    }
  }
}

// ---- attention: bf16 I/O (pitch 320), j-parallel 8 lanes/row, no-max softmax, swizzled LDS ----
__global__ __launch_bounds__(256)
void k_attn3(const __hip_bfloat16* __restrict__ Q, const __hip_bfloat16* __restrict__ Kb,
             const __hip_bfloat16* __restrict__ Vb, __hip_bfloat16* __restrict__ O)
{
  int b = blockIdx.x, h = blockIdx.y, tid = threadIdx.x;
  __shared__ float Ks[Tn][32];
  __shared__ float Vs[Tn][32];
  const size_t base = (size_t)b*Tn*Kp + h*30;
  for (int i = tid; i < Tn*32; i += 256) {
    int t = i >> 5, k = i & 31;
    float kv = 0.f, vv = 0.f;
    if (k < 30) {
      kv = __bfloat162float(Kb[base + (size_t)t*Kp + k]);
      vv = __bfloat162float(Vb[base + (size_t)t*Kp + k]);
    }
    int ss = (((k>>2) ^ (t&7))<<2) | (k&3);
    Ks[t][ss] = kv; Vs[t][ss] = vv;
  }
  __syncthreads();
  int lane = tid & 63;
  int w  = tid >> 6;
  int rg = lane >> 3;
  int jl = lane & 7;
  const float scale = 0.31622776601683794f;  // 1/sqrt(H)
  #pragma unroll 1
  for (int pass = 0; pass < 10; ++pass) {
    int row = pass*32 + w*8 + rg;
    bool valid = row < Tn;
    float q[32];
    if (valid) {
      const __hip_bfloat16* qp = Q + base + (size_t)row*Kp;
      #pragma unroll
      for (int k = 0; k < 30; ++k) q[k] = __bfloat162float(qp[k]);
    } else {
      #pragma unroll
      for (int k = 0; k < 30; ++k) q[k] = 0.f;
    }
    q[30] = 0.f; q[31] = 0.f;
    float l = 0.f, acc[32];
    #pragma unroll
    for (int k = 0; k < 32; ++k) acc[k] = 0.f;
    for (int j = jl; j < Tn; j += 8) {
      int sw = (j & 7) << 2;
      float s0 = 0.f, s1 = 0.f, s2 = 0.f, s3 = 0.f;
      #pragma unroll
      for (int oc = 0; oc < 8; ++oc) {
        const float4 kv = *reinterpret_cast<const float4*>(&Ks[j][(oc<<2) ^ sw]);
        s0 += q[oc*4+0]*kv.x; s1 += q[oc*4+1]*kv.y;
        s2 += q[oc*4+2]*kv.z; s3 += q[oc*4+3]*kv.w;
      }
      float p = __expf(((s0+s1)+(s2+s3))*scale);
      l += p;
      #pragma unroll
      for (int oc = 0; oc < 8; ++oc) {
        const float4 vv = *reinterpret_cast<const float4*>(&Vs[j][(oc<<2) ^ sw]);
        acc[oc*4+0] += p*vv.x; acc[oc*4+1] += p*vv.y;
        acc[oc*4+2] += p*vv.z; acc[oc*4+3] += p*vv.w;
      }
    }
    #pragma unroll
    for (int mask = 1; mask <= 4; mask <<= 1) {
      l += __shfl_xor(l, mask, 64);
      #pragma unroll
      for (int k = 0; k < 30; ++k) acc[k] += __shfl_xor(acc[k], mask, 64);
    }
    if (valid && jl == 0) {
      float inv = 1.f/l;
      __hip_bfloat16* op = O + base + (size_t)row*Kp;
      #pragma unroll
      for (int k = 0; k < 30; ++k) op[k] = __float2bfloat16(acc[k]*inv);
    }
  }
}

// ---- conv head reduce: G pitch 256 ----
__global__ __launch_bounds__(256)
void k_convred2(const float* __restrict__ G0, const float* __restrict__ G1,
                const float* __restrict__ bc1, const float* __restrict__ bc2,
                const float* __restrict__ bc3, const float* __restrict__ bc4,
                float* __restrict__ out100)
{
  int b = blockIdx.x, head = blockIdx.y;
  int kh  = head + 1;
  int off = (head == 0) ? 0 : (head == 1) ? 25 : (head == 2) ? 75 : 150;
  const float* bc = (head == 0) ? bc1 : (head == 1) ? bc2 : (head == 2) ? bc3 : bc4;
  int ncol = 25*kh;
  int ncp  = ncol | 1;
  int L = Tn - kh + 1;
  __shared__ float S[67*101];
  int tid = threadIdx.x, lane = tid & 63;
  float mx[7];
  #pragma unroll
  for (int u = 0; u < 7; ++u) mx[u] = -1e30f;
  for (int l0 = 0; l0 < L; l0 += 64) {
    int nrows = min(64 + kh - 1, Tn - l0);
    __syncthreads();
    for (int i = tid; i < nrows*ncol; i += 256) {
      int r = i / ncol, c = i % ncol;
      size_t g = (size_t)(b*Tn + l0 + r)*256 + off + c;
      S[r*ncp + c] = G0[g] + G1[g];
    }
    __syncthreads();
    int lmax = min(64, L - l0);
    #pragma unroll
    for (int u = 0; u < 7; ++u) {
      int o = (tid >> 6) + u*4;
      int dl = lane;
      if (o < 25 && dl < lmax) {
        float s = bc[o];
        for (int dh = 0; dh < kh; ++dh)
          s += S[(dl+dh)*ncp + o*kh + dh];
        mx[u] = fmaxf(mx[u], leaky(s));
      }
    }
  }
  #pragma unroll
  for (int u = 0; u < 7; ++u) {
    float v = mx[u];
    #pragma unroll
    for (int ofs = 32; ofs > 0; ofs >>= 1) v = fmaxf(v, __shfl_down(v, ofs, 64));
    int o = (tid >> 6) + u*4;
    if (lane == 0 && o < 25)
      out100[b*100 + head*25 + o] = v;
  }
}

// ---- final head ----
__global__ __launch_bounds__(320)
void k_final(const float* __restrict__ RTP, const float* __restrict__ out100,
             const float* __restrict__ Wlin, const float* __restrict__ blin,
             const float* __restrict__ Wlast, const float* __restrict__ blast,
             float* __restrict__ Y)
{
  int b = blockIdx.x, tid = threadIdx.x;
  __shared__ float cat[600];
  __shared__ float s100[100];
  __shared__ float red[5];
  if (tid < 100) s100[tid] = out100[b*100 + tid];
  if (tid < 300) cat[tid] = RTP[b*300 + tid];
  __syncthreads();
  if (tid < 300) {
    const float* w = Wlin + tid*100;
    float a = blin[tid];
    for (int j = 0; j < 100; ++j) a += s100[j]*w[j];
    cat[300 + tid] = leaky(a);
  }
  __syncthreads();
  for (int c = 0; c < 2; ++c) {
    float a = 0.f;
    for (int i = tid; i < 600; i += 320) a += cat[i]*Wlast[c*600 + i];
    a = blockSum<320>(a, red);
    if (tid == 0) Y[b*2 + c] = a + blast[c];
  }
}

extern "C" void kernel_launch(void* const* d_in, const int* in_sizes, int n_in,
                              void* d_out, int out_size, void* d_ws, size_t ws_size,
                              hipStream_t stream)
{
  (void)in_sizes; (void)n_in; (void)out_size; (void)ws_size;
  const float* x1    = (const float*)d_in[0];
  const float* x2    = (const float*)d_in[1];
  const float* Wimg  = (const float*)d_in[2];
  const float* bimg  = (const float*)d_in[3];
  const float* g1    = (const float*)d_in[4];
  const float* be1   = (const float*)d_in[5];
  const float* g2    = (const float*)d_in[6];
  const float* be2   = (const float*)d_in[7];
  const float* Wq_tp = (const float*)d_in[8];
  const float* Wk_tp = (const float*)d_in[9];
  const float* Wv_tp = (const float*)d_in[10];
  const float* Wv_pt = (const float*)d_in[13];   // Wq_pt/Wk_pt dead (softmax over size-1)
  const float* Wc1 = (const float*)d_in[26];
  const float* Wc2 = (const float*)d_in[27];
  const float* Wc3 = (const float*)d_in[28];
  const float* Wc4 = (const float*)d_in[29];
  const float* bc1 = (const float*)d_in[30];
  const float* bc2 = (const float*)d_in[31];
  const float* bc3 = (const float*)d_in[32];
  const float* bc4 = (const float*)d_in[33];
  const float* Wlin  = (const float*)d_in[34];
  const float* blin  = (const float*)d_in[35];
  const float* Wlast = (const float*)d_in[36];
  const float* blast = (const float*)d_in[37];

  char* base = (char*)d_ws;
  float* lnP    = (float*)(base + 0);        // 19200 f
  float* RTP    = (float*)(base + 76800);    // 19200 f
  float* vpt    = (float*)(base + 153600);   // 19200 f
  float* out100 = (float*)(base + 230400);   // 6400 f
  float* lnTf   = (float*)(base + 262144);   // [18624][300] f32 (22.35 MB) — dead after k_rptb
  float* G0     = (float*)(base + 262144);   // alias: [Mp][256] f32, written by conv GEMM later
  float* G1     = (float*)(base + 22610944); // [Mp][256] f32
  __hip_bfloat16* P0 = (__hip_bfloat16*)(base + 41747456);
  const size_t PS = (size_t)Mp*Kp;           // 5,980,160 elems (11.96 MB)
  __hip_bfloat16* P1 = P0 + PS;
  __hip_bfloat16* P2 = P1 + PS;
  __hip_bfloat16* P3 = P2 + PS;
  __hip_bfloat16* P4 = P3 + PS;
  __hip_bfloat16* Wb  = P4 + PS;             // 12 mats x [320][320]
  __hip_bfloat16* Wpb = Wb + 12*Kp*Kp;       // 2 x [256][320]
  const int WS = Kp*Kp;  // 102400

  // prologue (fp32)
  k_img_lnp<<<Bn, 256, 0, stream>>>(x2, Wimg, bimg, g2, be2, lnP);
  k_lnT<<<Bn, 1024, 0, stream>>>(x1, g1, be1, lnTf, P0);
  k_tp<<<Bn, 320, 0, stream>>>(lnP, lnTf, Wq_tp, Wk_tp, Wv_tp, Wv_pt, RTP, vpt);
  k_rptb<<<(Mn*Kp + 255)/256, 256, 0, stream>>>(lnTf, vpt, P1);

  // weight conversion
  Wptrs wp;
  for (int i = 0; i < 12; ++i) wp.p[i] = (const float*)d_in[14 + i];
  k_wcvt<<<(12*WS + 255)/256, 256, 0, stream>>>(wp, Wb);
  k_wpackb<<<(2*256*Kp + 255)/256, 256, 0, stream>>>(Wc1, Wc2, Wc3, Wc4, Wpb);

  dim3 gqkv(146, 5, 3), gone(146, 5, 1), gconv(146, 4, 2), gat(Bn, Hn);
  // L1: in=P0(lnT) -> Q=P2 K=P3 V=P4 ; attn O->P0 ; proj a1->P2
  k_mfma<__hip_bfloat16><<<gqkv, 256, 0, stream>>>(P0,P0,P0, Wb,Wb+WS,Wb+2*WS, P2,P3,P4, Kp);
  k_attn3<<<gat, 256, 0, stream>>>(P2, P3, P4, P0);
  k_mfma<__hip_bfloat16><<<gone, 256, 0, stream>>>(P0,P0,P0, Wb+3*WS,Wb+3*WS,Wb+3*WS, P2,P2,P2, Kp);
  // L2: in=P2(a1) -> Q=P0 K=P3 V=P4 ; attn O->P2 ; proj a2->P0
  k_mfma<__hip_bfloat16><<<gqkv, 256, 0, stream>>>(P2,P2,P2, Wb+4*WS,Wb+5*WS,Wb+6*WS, P0,P3,P4, Kp);
  k_attn3<<<gat, 256, 0, stream>>>(P0, P3, P4, P2);
  k_mfma<__hip_bfloat16><<<gone, 256, 0, stream>>>(P2,P2,P2, Wb+7*WS,Wb+7*WS,Wb+7*WS, P0,P0,P0, Kp);
  // L3: in=P0(a2) -> Q=P2 K=P3 V=P4 ; attn O->P0 ; proj a3->P2
  k_mfma<__hip_bfloat16><<<gqkv, 256, 0, stream>>>(P0,P0,P0, Wb+8*WS,Wb+9*WS,Wb+10*WS, P2,P3,P4, Kp);
  k_attn3<<<gat, 256, 0, stream>>>(P2, P3, P4, P0);
  k_mfma<__hip_bfloat16><<<gone, 256, 0, stream>>>(P0,P0,P0, Wb+11*WS,Wb+11*WS,Wb+11*WS, P2,P2,P2, Kp);
  // conv GEMMs: z0: G0 = rpt(P1) @ Wpb0.T ; z1: G1 = a3(P2) @ Wpb1.T  (fp32 out, pitch 256)
  k_mfma<float><<<gconv, 256, 0, stream>>>(P1,P2,P1, Wpb,Wpb+256*Kp,Wpb, G0,G1,G0, 256);
  k_convred2<<<dim3(Bn,4), 256, 0, stream>>>(G0, G1, bc1, bc2, bc3, bc4, out100);
  k_final<<<Bn, 320, 0, stream>>>(RTP, out100, Wlin, blin, Wlast, blast, (float*)d_out);
}

// Round 4
// 986.209 us; speedup vs baseline: 3.0899x; 1.4343x over previous
//
#include <hip/hip_runtime.h>
#include <hip/hip_bf16.h>
#include <math.h>

#define Bn 64
#define Tn 291
#define Dn 300
#define Hn 10
#define Mn (Bn*Tn)   // 18624
#define Mp 18688     // 146*128 padded rows
#define Kp 320       // padded K / activation pitch

typedef __bf16 bf16x8 __attribute__((ext_vector_type(8)));
typedef float f32x4 __attribute__((ext_vector_type(4)));

static __device__ __forceinline__ float leaky(float x){ return x >= 0.f ? x : 0.01f*x; }

template<int NT>
static __device__ __forceinline__ float blockSum(float v, float* red){
  __syncthreads();
  int lane = threadIdx.x & 63, wid = threadIdx.x >> 6;
  #pragma unroll
  for (int o = 32; o > 0; o >>= 1) v += __shfl_down(v, o, 64);
  if (lane == 0) red[wid] = v;
  __syncthreads();
  if (threadIdx.x == 0) {
    float s = red[0];
    #pragma unroll
    for (int w = 1; w < NT/64; ++w) s += red[w];
    red[0] = s;
  }
  __syncthreads();
  return red[0];
}

template<int NT>
static __device__ __forceinline__ float blockMax(float v, float* red){
  __syncthreads();
  int lane = threadIdx.x & 63, wid = threadIdx.x >> 6;
  #pragma unroll
  for (int o = 32; o > 0; o >>= 1) v = fmaxf(v, __shfl_down(v, o, 64));
  if (lane == 0) red[wid] = v;
  __syncthreads();
  if (threadIdx.x == 0) {
    float s = red[0];
    #pragma unroll
    for (int w = 1; w < NT/64; ++w) s = fmaxf(s, red[w]);
    red[0] = s;
  }
  __syncthreads();
  return red[0];
}

// ---- image branch ----
__global__ __launch_bounds__(256)
void k_img_lnp(const float* __restrict__ x2, const float* __restrict__ Wimg,
               const float* __restrict__ bimg, const float* __restrict__ g2,
               const float* __restrict__ be2, float* __restrict__ lnP)
{
  int b = blockIdx.x, tid = threadIdx.x;
  __shared__ float sx[1000];
  __shared__ float sy[300];
  __shared__ float red[4];
  for (int i = tid; i < 1000; i += 256) sx[i] = x2[b*1000 + i];
  __syncthreads();
  for (int j = tid; j < 300; j += 256) {
    const float* w = Wimg + j*1000;
    float a = 0.f;
    for (int i = 0; i < 1000; ++i) a += sx[i]*w[i];
    sy[j] = leaky(a + bimg[j]);
  }
  __syncthreads();
  float s = 0.f, ss = 0.f;
  for (int j = tid; j < 300; j += 256) { float v = sy[j]; s += v; ss += v*v; }
  float tot  = blockSum<256>(s, red);
  float tot2 = blockSum<256>(ss, red);
  float mu   = tot * (1.f/300.f);
  float var  = tot2 * (1.f/300.f) - mu*mu;
  float rstd = rsqrtf(var + 1e-5f);
  for (int j = tid; j < 300; j += 256)
    lnP[b*300 + j] = (sy[j]-mu)*rstd*g2[j] + be2[j];
}

// ---- lnT: LayerNorm over (291,300); fp32 (pitch 300) + bf16 (pitch 320, zero-padded) ----
__global__ __launch_bounds__(1024)
void k_lnT(const float* __restrict__ x1, const float* __restrict__ g1,
           const float* __restrict__ be1, float* __restrict__ outf,
           __hip_bfloat16* __restrict__ outb)
{
  int b = blockIdx.x, tid = threadIdx.x;
  __shared__ float red[16];
  const float4* xb = (const float4*)(x1 + (size_t)b*87300);
  const float4* g4 = (const float4*)g1;
  const float4* b4 = (const float4*)be1;
  float4* o4 = (float4*)(outf + (size_t)b*87300);
  float s = 0.f, ss = 0.f;
  for (int i = tid; i < 21825; i += 1024) {
    float4 v = xb[i];
    s  += v.x+v.y+v.z+v.w;
    ss += v.x*v.x+v.y*v.y+v.z*v.z+v.w*v.w;
  }
  float tot  = blockSum<1024>(s, red);
  float tot2 = blockSum<1024>(ss, red);
  float mu   = tot / 87300.f;
  float var  = tot2 / 87300.f - mu*mu;
  float rstd = rsqrtf(var + 1e-5f);
  for (int i = tid; i < 21825; i += 1024) {
    float4 v = xb[i], g = g4[i], be = b4[i], o;
    o.x = (v.x-mu)*rstd*g.x + be.x;
    o.y = (v.y-mu)*rstd*g.y + be.y;
    o.z = (v.z-mu)*rstd*g.z + be.z;
    o.w = (v.w-mu)*rstd*g.w + be.w;
    o4[i] = o;
  }
  const float* xs = x1 + (size_t)b*87300;
  for (int e = tid; e < Tn*Dn; e += 1024) {
    int t = e/300;
    float x = xs[e];
    outb[(size_t)(b*Tn+t)*Kp + (e - t*300)] = __float2bfloat16((x-mu)*rstd*g1[e] + be1[e]);
  }
  for (int e = tid; e < Tn*20; e += 1024) {
    int t = e/20, d = 300 + e%20;
    outb[(size_t)(b*Tn+t)*Kp + d] = __float2bfloat16(0.f);
  }
}

// ---- T->P cross attention (single query) + v for P->T branch ----
__global__ __launch_bounds__(320)
void k_tp(const float* __restrict__ lnP, const float* __restrict__ lnT,
          const float* __restrict__ Wq, const float* __restrict__ Wk,
          const float* __restrict__ Wv, const float* __restrict__ Wvpt,
          float* __restrict__ RTP, float* __restrict__ vpt)
{
  int b = blockIdx.x, tid = threadIdx.x;
  __shared__ float sP[300], sQ[300], sM[300], sA[291], sW[300], red[5];
  if (tid < 300) sP[tid] = lnP[b*300 + tid];
  __syncthreads();
  if (tid < 300) {
    const float* w = Wq + tid*300;
    float a = 0.f;
    for (int i = 0; i < 300; ++i) a += sP[i]*w[i];
    sQ[tid] = a;
  }
  __syncthreads();
  if (tid < 300) {
    float a = 0.f;
    for (int j = 0; j < 300; ++j) a += sQ[j]*Wk[j*300 + tid];
    sM[tid] = a;
  }
  __syncthreads();
  float sc = -1e30f;
  if (tid < 291) {
    const float* r = lnT + ((size_t)b*Tn + tid)*300;
    float a = 0.f;
    for (int i = 0; i < 300; ++i) a += r[i]*sM[i];
    sc = a;
  }
  float mx  = blockMax<320>(sc, red);
  float e   = (tid < 291) ? __expf(sc - mx) : 0.f;
  float den = blockSum<320>(e, red);
  if (tid < 291) sA[tid] = e;
  __syncthreads();
  if (tid < 300) {
    float a = 0.f;
    for (int t = 0; t < 291; ++t) a += sA[t]*lnT[((size_t)b*Tn + t)*300 + tid];
    sW[tid] = a / den;
  }
  __syncthreads();
  if (tid < 300) {
    const float* w = Wv + tid*300;
    float a = 0.f;
    for (int i = 0; i < 300; ++i) a += sW[i]*w[i];
    RTP[b*300 + tid] = a + sP[tid];
    const float* w2 = Wvpt + tid*300;
    float a2 = 0.f;
    for (int i = 0; i < 300; ++i) a2 += sP[i]*w2[i];
    vpt[b*300 + tid] = a2;
  }
}

// ---- rpt = lnT + vpt (broadcast over t), bf16 pitch-320 zero-padded ----
__global__ __launch_bounds__(256)
void k_rptb(const float* __restrict__ lnT, const float* __restrict__ vpt,
            __hip_bfloat16* __restrict__ out)
{
  int idx = blockIdx.x*256 + threadIdx.x;
  if (idx >= Mn*Kp) return;
  int m = idx / Kp, d = idx - m*Kp;
  int b = m / Tn;
  float v = (d < 300) ? lnT[(size_t)m*300 + d] + vpt[b*300 + d] : 0.f;
  out[idx] = __float2bfloat16(v);
}

// ---- convert 12 square weights fp32[300][300] -> bf16[320][320] zero-padded ----
struct Wptrs { const float* p[12]; };
__global__ __launch_bounds__(256)
void k_wcvt(Wptrs wp, __hip_bfloat16* __restrict__ out)
{
  int idx = blockIdx.x*256 + threadIdx.x;
  if (idx >= 12*Kp*Kp) return;
  int mat = idx / (Kp*Kp);
  int rem = idx - mat*(Kp*Kp);
  int r = rem / Kp, c = rem - r*Kp;
  float v = (r < 300 && c < 300) ? wp.p[mat][r*300 + c] : 0.f;
  out[idx] = __float2bfloat16(v);
}

// ---- pack conv weights -> bf16 [2][256][320] zero-padded ----
__global__ __launch_bounds__(256)
void k_wpackb(const float* __restrict__ Wc1, const float* __restrict__ Wc2,
              const float* __restrict__ Wc3, const float* __restrict__ Wc4,
              __hip_bfloat16* __restrict__ out)
{
  int idx = blockIdx.x*256 + threadIdx.x;
  if (idx >= 2*256*Kp) return;
  int c  = idx % Kp;
  int rc = idx / Kp;
  int ch = rc / 256;
  int r  = rc % 256;
  float v = 0.f;
  if (r < 250 && c < 300) {
    const float* W; int kh, ro;
    if      (r < 25)  { W = Wc1; kh = 1; ro = r;      }
    else if (r < 75)  { W = Wc2; kh = 2; ro = r - 25; }
    else if (r < 150) { W = Wc3; kh = 3; ro = r - 75; }
    else              { W = Wc4; kh = 4; ro = r - 150;}
    int o = ro/kh, dh = ro%kh;
    v = W[((o*2 + ch)*kh + dh)*300 + c];
  }
  out[idx] = __float2bfloat16(v);
}

// ---- store helpers ----
static __device__ __forceinline__ void cvt_store(__hip_bfloat16* p, float v){ *p = __float2bfloat16(v); }
static __device__ __forceinline__ void cvt_store(float* p, float v){ *p = v; }

// ---- bf16 MFMA GEMM: C[m,n] = sum_k A[m,k]*W[n,k]. A:[Mp][320] bf16, W:[pitchN][320] bf16.
//      128x64 tile, 4 waves, 5 K-tiles of 64, double-buffered LDS, XOR swizzle.
//      HEADPAD: C col n -> (n/30)*32 + n%30 (pitch 320), head pad cols zeroed. ----
template<typename OutT, bool HEADPAD>
__global__ __launch_bounds__(256)
void k_mfma(const __hip_bfloat16* __restrict__ A0, const __hip_bfloat16* __restrict__ A1,
            const __hip_bfloat16* __restrict__ A2,
            const __hip_bfloat16* __restrict__ W0, const __hip_bfloat16* __restrict__ W1,
            const __hip_bfloat16* __restrict__ W2,
            OutT* __restrict__ C0, OutT* __restrict__ C1, OutT* __restrict__ C2,
            int pitch)
{
  const ushort* A = (const ushort*)(blockIdx.z==0 ? A0 : blockIdx.z==1 ? A1 : A2);
  const ushort* W = (const ushort*)(blockIdx.z==0 ? W0 : blockIdx.z==1 ? W1 : W2);
  OutT*         C = blockIdx.z==0 ? C0 : blockIdx.z==1 ? C1 : C2;
  int m0 = blockIdx.x*128, n0 = blockIdx.y*64;
  __shared__ alignas(16) ushort As[2][128*64];
  __shared__ alignas(16) ushort Bs[2][64*64];
  int tid = threadIdx.x;
  int lane = tid & 63, w = tid >> 6, wr = w >> 1, wc = w & 1;
  int lm = lane & 15, lk = lane >> 4;
  f32x4 acc[4][2] = {};
  uint4 ra[4], rw[2];

  auto loadregs = [&](int kt){
    #pragma unroll
    for (int u = 0; u < 4; ++u) {
      int s = tid + u*256; int row = s >> 3, kg = s & 7;
      ra[u] = *(const uint4*)(A + (size_t)(m0+row)*Kp + kt*64 + kg*8);
    }
    #pragma unroll
    for (int u = 0; u < 2; ++u) {
      int s = tid + u*256; int row = s >> 3, kg = s & 7;
      rw[u] = *(const uint4*)(W + (size_t)(n0+row)*Kp + kt*64 + kg*8);
    }
  };
  auto writeLDS = [&](int buf){
    #pragma unroll
    for (int u = 0; u < 4; ++u) {
      int s = tid + u*256; int row = s >> 3, kg = s & 7;
      *(uint4*)&As[buf][row*64 + ((kg ^ (row&7)) << 3)] = ra[u];
    }
    #pragma unroll
    for (int u = 0; u < 2; ++u) {
      int s = tid + u*256; int row = s >> 3, kg = s & 7;
      *(uint4*)&Bs[buf][row*64 + ((kg ^ (row&7)) << 3)] = rw[u];
    }
  };
  auto compute = [&](int buf){
    #pragma unroll
    for (int s = 0; s < 2; ++s) {
      bf16x8 af[4], bfr[2];
      int kg = s*4 + lk;
      #pragma unroll
      for (int mf = 0; mf < 4; ++mf) {
        int r = wr*64 + mf*16 + lm;
        af[mf] = *(const bf16x8*)&As[buf][r*64 + ((kg ^ (r&7)) << 3)];
      }
      #pragma unroll
      for (int nf = 0; nf < 2; ++nf) {
        int r = wc*32 + nf*16 + lm;
        bfr[nf] = *(const bf16x8*)&Bs[buf][r*64 + ((kg ^ (r&7)) << 3)];
      }
      #pragma unroll
      for (int mf = 0; mf < 4; ++mf)
        #pragma unroll
        for (int nf = 0; nf < 2; ++nf)
          acc[mf][nf] = __builtin_amdgcn_mfma_f32_16x16x32_bf16(af[mf], bfr[nf], acc[mf][nf], 0, 0, 0);
    }
  };

  loadregs(0); writeLDS(0);
  __syncthreads();
  #pragma unroll 1
  for (int kt = 0; kt < 5; ++kt) {
    if (kt < 4) loadregs(kt+1);
    compute(kt & 1);
    if (kt < 4) {
      __syncthreads();
      writeLDS((kt+1) & 1);
      __syncthreads();
    }
  }
  #pragma unroll
  for (int mf = 0; mf < 4; ++mf) {
    #pragma unroll
    for (int i = 0; i < 4; ++i) {
      int m = m0 + wr*64 + mf*16 + lk*4 + i;
      #pragma unroll
      for (int nf = 0; nf < 2; ++nf) {
        int n = n0 + wc*32 + nf*16 + lm;
        if (HEADPAD) {
          if (n < 300) {
            int hh = n/30, col = hh*32 + (n - hh*30);
            cvt_store(C + (size_t)m*Kp + col, acc[mf][nf][i]);
          }
        } else {
          cvt_store(C + (size_t)m*pitch + n, acc[mf][nf][i]);
        }
      }
    }
  }
  if (HEADPAD && blockIdx.y == 0) {
    // zero the 20 head-pad columns for this row range
    for (int e = tid; e < 128*20; e += 256) {
      int row = e/20, c = e - (e/20)*20;
      int col = (c>>1)*32 + 30 + (c&1);
      cvt_store(C + (size_t)(m0+row)*Kp + col, 0.f);
    }
  }
}

// ---- MFMA flash attention, one block per (b,h), no-max softmax.
//      Q/K/V in head-padded layout [row][h*32+d], O written in normal layout [row][h*30+d]. ----
__global__ __launch_bounds__(256)
void k_attn4(const __hip_bfloat16* __restrict__ Q, const __hip_bfloat16* __restrict__ Kb,
             const __hip_bfloat16* __restrict__ Vb, __hip_bfloat16* __restrict__ O)
{
  int b = blockIdx.x, h = blockIdx.y, tid = threadIdx.x;
  __shared__ alignas(16) ushort Ks[320*40];   // K rows, pitch 40 (2-way free)
  __shared__ alignas(16) ushort Vt[32*328];   // V^T rows d, pitch 328 (2-way free)
  __shared__ alignas(16) ushort Ps[64*328];   // P rows q (per q-tile), pitch 328
  const size_t hbase = (size_t)b*Tn*Kp + h*32;
  // stage K [320][40], zero rows >= Tn (cols 30,31 already zero via HEADPAD)
  for (int i = tid; i < 320*4; i += 256) {
    int r = i >> 2, g = i & 3;
    uint4 v = make_uint4(0u,0u,0u,0u);
    if (r < Tn) v = *(const uint4*)((const ushort*)Kb + hbase + (size_t)r*Kp + g*8);
    *(uint4*)&Ks[r*40 + g*8] = v;
  }
  // stage V transposed: Vt[d][j]; e-order staggered per g to avoid bank conflicts
  for (int i = tid; i < 320*4; i += 256) {
    int j = i >> 2, g = i & 3;
    uint4 v = make_uint4(0u,0u,0u,0u);
    if (j < Tn) v = *(const uint4*)((const ushort*)Vb + hbase + (size_t)j*Kp + g*8);
    const ushort* pv = (const ushort*)&v;
    #pragma unroll
    for (int ee = 0; ee < 8; ++ee) {
      int e = (ee + g*2) & 7;
      Vt[(g*8+e)*328 + j] = pv[e];
    }
  }
  __syncthreads();
  int lane = tid & 63, w = tid >> 6;
  int lm = lane & 15, lk = lane >> 4;
  int qloc = w*16 + lm;
  const float scale = 0.31622776601683794f;  // 1/sqrt(H)
  #pragma unroll 1
  for (int qt = 0; qt < 5; ++qt) {
    int qrow = qt*64 + w*16 + lm;   // may exceed Tn (reads next sample's rows; masked at store)
    bf16x8 qf = *(const bf16x8*)((const ushort*)Q + ((size_t)b*Tn + qrow)*Kp + h*32 + lk*8);
    float rsum = 0.f;
    // S^T = K Q^T via mfma(Kfrag, Qfrag): lane -> S^T[j=jt*16+lk*4+i][q=...+lm]
    #pragma unroll 1
    for (int jt = 0; jt < 20; ++jt) {
      bf16x8 kf = *(const bf16x8*)&Ks[(jt*16+lm)*40 + lk*8];
      f32x4 s = {};
      s = __builtin_amdgcn_mfma_f32_16x16x32_bf16(kf, qf, s, 0, 0, 0);
      union { ushort u[4]; uint2 v; } pk;
      #pragma unroll
      for (int i2 = 0; i2 < 4; ++i2) {
        int j = jt*16 + lk*4 + i2;
        float p = (j < Tn) ? __expf(s[i2]*scale) : 0.f;
        rsum += p;
        __hip_bfloat16 t = __float2bfloat16(p);
        pk.u[i2] = *reinterpret_cast<ushort*>(&t);
      }
      *(uint2*)&Ps[qloc*328 + jt*16 + lk*4] = pk.v;
    }
    rsum += __shfl_xor(rsum, 16, 64);
    rsum += __shfl_xor(rsum, 32, 64);   // all lanes: rsum for q-row lm of this wave
    // O = P V via mfma(Pfrag, Vtfrag): lane -> O[q=lk*4+i][d=nf*16+lm]
    f32x4 oacc[2] = {};
    #pragma unroll
    for (int kt = 0; kt < 10; ++kt) {
      bf16x8 pf = *(const bf16x8*)&Ps[qloc*328 + kt*32 + lk*8];
      #pragma unroll
      for (int nf = 0; nf < 2; ++nf) {
        bf16x8 vf = *(const bf16x8*)&Vt[(nf*16+lm)*328 + kt*32 + lk*8];
        oacc[nf] = __builtin_amdgcn_mfma_f32_16x16x32_bf16(pf, vf, oacc[nf], 0, 0, 0);
      }
    }
    float inv[4];
    #pragma unroll
    for (int i2 = 0; i2 < 4; ++i2) inv[i2] = 1.f / __shfl(rsum, lk*4 + i2, 64);
    #pragma unroll
    for (int nf = 0; nf < 2; ++nf) {
      int d = nf*16 + lm;
      if (d < 30) {
        #pragma unroll
        for (int i2 = 0; i2 < 4; ++i2) {
          int q = qt*64 + w*16 + lk*4 + i2;
          if (q < Tn)
            O[((size_t)b*Tn + q)*Kp + h*30 + d] = __float2bfloat16(oacc[nf][i2]*inv[i2]);
        }
      }
    }
  }
}

// ---- conv head reduce: G pitch 256 ----
__global__ __launch_bounds__(256)
void k_convred2(const float* __restrict__ G0, const float* __restrict__ G1,
                const float* __restrict__ bc1, const float* __restrict__ bc2,
                const float* __restrict__ bc3, const float* __restrict__ bc4,
                float* __restrict__ out100)
{
  int b = blockIdx.x, head = blockIdx.y;
  int kh  = head + 1;
  int off = (head == 0) ? 0 : (head == 1) ? 25 : (head == 2) ? 75 : 150;
  const float* bc = (head == 0) ? bc1 : (head == 1) ? bc2 : (head == 2) ? bc3 : bc4;
  int ncol = 25*kh;
  int ncp  = ncol | 1;
  int L = Tn - kh + 1;
  __shared__ float S[67*101];
  int tid = threadIdx.x, lane = tid & 63;
  float mx[7];
  #pragma unroll
  for (int u = 0; u < 7; ++u) mx[u] = -1e30f;
  for (int l0 = 0; l0 < L; l0 += 64) {
    int nrows = min(64 + kh - 1, Tn - l0);
    __syncthreads();
    for (int i = tid; i < nrows*ncol; i += 256) {
      int r = i / ncol, c = i % ncol;
      size_t g = (size_t)(b*Tn + l0 + r)*256 + off + c;
      S[r*ncp + c] = G0[g] + G1[g];
    }
    __syncthreads();
    int lmax = min(64, L - l0);
    #pragma unroll
    for (int u = 0; u < 7; ++u) {
      int o = (tid >> 6) + u*4;
      int dl = lane;
      if (o < 25 && dl < lmax) {
        float s = bc[o];
        for (int dh = 0; dh < kh; ++dh)
          s += S[(dl+dh)*ncp + o*kh + dh];
        mx[u] = fmaxf(mx[u], leaky(s));
      }
    }
  }
  #pragma unroll
  for (int u = 0; u < 7; ++u) {
    float v = mx[u];
    #pragma unroll
    for (int ofs = 32; ofs > 0; ofs >>= 1) v = fmaxf(v, __shfl_down(v, ofs, 64));
    int o = (tid >> 6) + u*4;
    if (lane == 0 && o < 25)
      out100[b*100 + head*25 + o] = v;
  }
}

// ---- final head ----
__global__ __launch_bounds__(320)
void k_final(const float* __restrict__ RTP, const float* __restrict__ out100,
             const float* __restrict__ Wlin, const float* __restrict__ blin,
             const float* __restrict__ Wlast, const float* __restrict__ blast,
             float* __restrict__ Y)
{
  int b = blockIdx.x, tid = threadIdx.x;
  __shared__ float cat[600];
  __shared__ float s100[100];
  __shared__ float red[5];
  if (tid < 100) s100[tid] = out100[b*100 + tid];
  if (tid < 300) cat[tid] = RTP[b*300 + tid];
  __syncthreads();
  if (tid < 300) {
    const float* w = Wlin + tid*100;
    float a = blin[tid];
    for (int j = 0; j < 100; ++j) a += s100[j]*w[j];
    cat[300 + tid] = leaky(a);
  }
  __syncthreads();
  for (int c = 0; c < 2; ++c) {
    float a = 0.f;
    for (int i = tid; i < 600; i += 320) a += cat[i]*Wlast[c*600 + i];
    a = blockSum<320>(a, red);
    if (tid == 0) Y[b*2 + c] = a + blast[c];
  }
}

extern "C" void kernel_launch(void* const* d_in, const int* in_sizes, int n_in,
                              void* d_out, int out_size, void* d_ws, size_t ws_size,
                              hipStream_t stream)
{
  (void)in_sizes; (void)n_in; (void)out_size; (void)ws_size;
  const float* x1    = (const float*)d_in[0];
  const float* x2    = (const float*)d_in[1];
  const float* Wimg  = (const float*)d_in[2];
  const float* bimg  = (const float*)d_in[3];
  const float* g1    = (const float*)d_in[4];
  const float* be1   = (const float*)d_in[5];
  const float* g2    = (const float*)d_in[6];
  const float* be2   = (const float*)d_in[7];
  const float* Wq_tp = (const float*)d_in[8];
  const float* Wk_tp = (const float*)d_in[9];
  const float* Wv_tp = (const float*)d_in[10];
  const float* Wv_pt = (const float*)d_in[13];   // Wq_pt/Wk_pt dead (softmax over size-1)
  const float* Wc1 = (const float*)d_in[26];
  const float* Wc2 = (const float*)d_in[27];
  const float* Wc3 = (const float*)d_in[28];
  const float* Wc4 = (const float*)d_in[29];
  const float* bc1 = (const float*)d_in[30];
  const float* bc2 = (const float*)d_in[31];
  const float* bc3 = (const float*)d_in[32];
  const float* bc4 = (const float*)d_in[33];
  const float* Wlin  = (const float*)d_in[34];
  const float* blin  = (const float*)d_in[35];
  const float* Wlast = (const float*)d_in[36];
  const float* blast = (const float*)d_in[37];

  char* base = (char*)d_ws;
  float* lnP    = (float*)(base + 0);
  float* RTP    = (float*)(base + 76800);
  float* vpt    = (float*)(base + 153600);
  float* out100 = (float*)(base + 230400);
  float* lnTf   = (float*)(base + 262144);   // fp32 lnT, dead after k_rptb
  float* G0     = (float*)(base + 262144);   // alias, written by conv GEMM later
  float* G1     = (float*)(base + 22610944);
  __hip_bfloat16* P0 = (__hip_bfloat16*)(base + 41747456);
  const size_t PS = (size_t)Mp*Kp;
  __hip_bfloat16* P1 = P0 + PS;
  __hip_bfloat16* P2 = P1 + PS;
  __hip_bfloat16* P3 = P2 + PS;
  __hip_bfloat16* P4 = P3 + PS;
  __hip_bfloat16* Wb  = P4 + PS;             // 12 x [320][320]
  __hip_bfloat16* Wpb = Wb + 12*Kp*Kp;       // 2 x [256][320]
  const int WS = Kp*Kp;

  // prologue (fp32)
  k_img_lnp<<<Bn, 256, 0, stream>>>(x2, Wimg, bimg, g2, be2, lnP);
  k_lnT<<<Bn, 1024, 0, stream>>>(x1, g1, be1, lnTf, P0);
  k_tp<<<Bn, 320, 0, stream>>>(lnP, lnTf, Wq_tp, Wk_tp, Wv_tp, Wv_pt, RTP, vpt);
  k_rptb<<<(Mn*Kp + 255)/256, 256, 0, stream>>>(lnTf, vpt, P1);

  Wptrs wp;
  for (int i = 0; i < 12; ++i) wp.p[i] = (const float*)d_in[14 + i];
  k_wcvt<<<(12*WS + 255)/256, 256, 0, stream>>>(wp, Wb);
  k_wpackb<<<(2*256*Kp + 255)/256, 256, 0, stream>>>(Wc1, Wc2, Wc3, Wc4, Wpb);

  dim3 gqkv(146, 5, 3), gone(146, 5, 1), gconv(146, 4, 2), gat(Bn, Hn);
  // L1: in=P0(lnT) -> Q=P2 K=P3 V=P4 (head-padded); attn O->P0 ; proj a1->P2
  k_mfma<__hip_bfloat16,true ><<<gqkv, 256, 0, stream>>>(P0,P0,P0, Wb,Wb+WS,Wb+2*WS, P2,P3,P4, Kp);
  k_attn4<<<gat, 256, 0, stream>>>(P2, P3, P4, P0);
  k_mfma<__hip_bfloat16,false><<<gone, 256, 0, stream>>>(P0,P0,P0, Wb+3*WS,Wb+3*WS,Wb+3*WS, P2,P2,P2, Kp);
  // L2: in=P2(a1) -> Q=P0 K=P3 V=P4 ; attn O->P2 ; proj a2->P0
  k_mfma<__hip_bfloat16,true ><<<gqkv, 256, 0, stream>>>(P2,P2,P2, Wb+4*WS,Wb+5*WS,Wb+6*WS, P0,P3,P4, Kp);
  k_attn4<<<gat, 256, 0, stream>>>(P0, P3, P4, P2);
  k_mfma<__hip_bfloat16,false><<<gone, 256, 0, stream>>>(P2,P2,P2, Wb+7*WS,Wb+7*WS,Wb+7*WS, P0,P0,P0, Kp);
  // L3: in=P0(a2) -> Q=P2 K=P3 V=P4 ; attn O->P0 ; proj a3->P2
  k_mfma<__hip_bfloat16,true ><<<gqkv, 256, 0, stream>>>(P0,P0,P0, Wb+8*WS,Wb+9*WS,Wb+10*WS, P2,P3,P4, Kp);
  k_attn4<<<gat, 256, 0, stream>>>(P2, P3, P4, P0);
  k_mfma<__hip_bfloat16,false><<<gone, 256, 0, stream>>>(P0,P0,P0, Wb+11*WS,Wb+11*WS,Wb+11*WS, P2,P2,P2, Kp);
  // conv GEMMs: G0 = rpt(P1) @ Wpb0.T ; G1 = a3(P2) @ Wpb1.T  (fp32 out, pitch 256)
  k_mfma<float,false><<<gconv, 256, 0, stream>>>(P1,P2,P1, Wpb,Wpb+256*Kp,Wpb, G0,G1,G0, 256);
  k_convred2<<<dim3(Bn,4), 256, 0, stream>>>(G0, G1, bc1, bc2, bc3, bc4, out100);
  k_final<<<Bn, 320, 0, stream>>>(RTP, out100, Wlin, blin, Wlast, blast, (float*)d_out);
}

// Round 5
// 928.308 us; speedup vs baseline: 3.2826x; 1.0624x over previous
//
#include <hip/hip_runtime.h>
#include <hip/hip_bf16.h>
#include <math.h>

#define Bn 64
#define Tn 291
#define Dn 300
#define Hn 10
#define Mn (Bn*Tn)   // 18624
#define Mp 18688     // 292*64 padded rows
#define Kp 320       // padded K / activation pitch

typedef __bf16 bf16x8 __attribute__((ext_vector_type(8)));
typedef float f32x4 __attribute__((ext_vector_type(4)));

static __device__ __forceinline__ float leaky(float x){ return x >= 0.f ? x : 0.01f*x; }

template<int NT>
static __device__ __forceinline__ float blockSum(float v, float* red){
  __syncthreads();
  int lane = threadIdx.x & 63, wid = threadIdx.x >> 6;
  #pragma unroll
  for (int o = 32; o > 0; o >>= 1) v += __shfl_down(v, o, 64);
  if (lane == 0) red[wid] = v;
  __syncthreads();
  if (threadIdx.x == 0) {
    float s = red[0];
    #pragma unroll
    for (int w = 1; w < NT/64; ++w) s += red[w];
    red[0] = s;
  }
  __syncthreads();
  return red[0];
}

template<int NT>
static __device__ __forceinline__ float blockMax(float v, float* red){
  __syncthreads();
  int lane = threadIdx.x & 63, wid = threadIdx.x >> 6;
  #pragma unroll
  for (int o = 32; o > 0; o >>= 1) v = fmaxf(v, __shfl_down(v, o, 64));
  if (lane == 0) red[wid] = v;
  __syncthreads();
  if (threadIdx.x == 0) {
    float s = red[0];
    #pragma unroll
    for (int w = 1; w < NT/64; ++w) s = fmaxf(s, red[w]);
    red[0] = s;
  }
  __syncthreads();
  return red[0];
}

// ---- image branch ----
__global__ __launch_bounds__(256)
void k_img_lnp(const float* __restrict__ x2, const float* __restrict__ Wimg,
               const float* __restrict__ bimg, const float* __restrict__ g2,
               const float* __restrict__ be2, float* __restrict__ lnP)
{
  int b = blockIdx.x, tid = threadIdx.x;
  __shared__ float sx[1000];
  __shared__ float sy[300];
  __shared__ float red[4];
  for (int i = tid; i < 1000; i += 256) sx[i] = x2[b*1000 + i];
  __syncthreads();
  for (int j = tid; j < 300; j += 256) {
    const float* w = Wimg + j*1000;
    float a = 0.f;
    for (int i = 0; i < 1000; ++i) a += sx[i]*w[i];
    sy[j] = leaky(a + bimg[j]);
  }
  __syncthreads();
  float s = 0.f, ss = 0.f;
  for (int j = tid; j < 300; j += 256) { float v = sy[j]; s += v; ss += v*v; }
  float tot  = blockSum<256>(s, red);
  float tot2 = blockSum<256>(ss, red);
  float mu   = tot * (1.f/300.f);
  float var  = tot2 * (1.f/300.f) - mu*mu;
  float rstd = rsqrtf(var + 1e-5f);
  for (int j = tid; j < 300; j += 256)
    lnP[b*300 + j] = (sy[j]-mu)*rstd*g2[j] + be2[j];
}

// ---- lnT: LayerNorm over (291,300); fp32 (pitch 300) + bf16 (pitch 320, zero-padded) ----
__global__ __launch_bounds__(1024)
void k_lnT(const float* __restrict__ x1, const float* __restrict__ g1,
           const float* __restrict__ be1, float* __restrict__ outf,
           __hip_bfloat16* __restrict__ outb)
{
  int b = blockIdx.x, tid = threadIdx.x;
  __shared__ float red[16];
  const float4* xb = (const float4*)(x1 + (size_t)b*87300);
  const float4* g4 = (const float4*)g1;
  const float4* b4 = (const float4*)be1;
  float4* o4 = (float4*)(outf + (size_t)b*87300);
  float s = 0.f, ss = 0.f;
  for (int i = tid; i < 21825; i += 1024) {
    float4 v = xb[i];
    s  += v.x+v.y+v.z+v.w;
    ss += v.x*v.x+v.y*v.y+v.z*v.z+v.w*v.w;
  }
  float tot  = blockSum<1024>(s, red);
  float tot2 = blockSum<1024>(ss, red);
  float mu   = tot / 87300.f;
  float var  = tot2 / 87300.f - mu*mu;
  float rstd = rsqrtf(var + 1e-5f);
  for (int i = tid; i < 21825; i += 1024) {
    float4 v = xb[i], g = g4[i], be = b4[i], o;
    o.x = (v.x-mu)*rstd*g.x + be.x;
    o.y = (v.y-mu)*rstd*g.y + be.y;
    o.z = (v.z-mu)*rstd*g.z + be.z;
    o.w = (v.w-mu)*rstd*g.w + be.w;
    o4[i] = o;
  }
  const float* xs = x1 + (size_t)b*87300;
  for (int e = tid; e < Tn*Dn; e += 1024) {
    int t = e/300;
    float x = xs[e];
    outb[(size_t)(b*Tn+t)*Kp + (e - t*300)] = __float2bfloat16((x-mu)*rstd*g1[e] + be1[e]);
  }
  for (int e = tid; e < Tn*20; e += 1024) {
    int t = e/20, d = 300 + e%20;
    outb[(size_t)(b*Tn+t)*Kp + d] = __float2bfloat16(0.f);
  }
}

// ---- T->P cross attention (single query) + v for P->T branch ----
__global__ __launch_bounds__(320)
void k_tp(const float* __restrict__ lnP, const float* __restrict__ lnT,
          const float* __restrict__ Wq, const float* __restrict__ Wk,
          const float* __restrict__ Wv, const float* __restrict__ Wvpt,
          float* __restrict__ RTP, float* __restrict__ vpt)
{
  int b = blockIdx.x, tid = threadIdx.x;
  __shared__ float sP[300], sQ[300], sM[300], sA[291], sW[300], red[5];
  if (tid < 300) sP[tid] = lnP[b*300 + tid];
  __syncthreads();
  if (tid < 300) {
    const float* w = Wq + tid*300;
    float a = 0.f;
    for (int i = 0; i < 300; ++i) a += sP[i]*w[i];
    sQ[tid] = a;
  }
  __syncthreads();
  if (tid < 300) {
    float a = 0.f;
    for (int j = 0; j < 300; ++j) a += sQ[j]*Wk[j*300 + tid];
    sM[tid] = a;
  }
  __syncthreads();
  float sc = -1e30f;
  if (tid < 291) {
    const float* r = lnT + ((size_t)b*Tn + tid)*300;
    float a = 0.f;
    for (int i = 0; i < 300; ++i) a += r[i]*sM[i];
    sc = a;
  }
  float mx  = blockMax<320>(sc, red);
  float e   = (tid < 291) ? __expf(sc - mx) : 0.f;
  float den = blockSum<320>(e, red);
  if (tid < 291) sA[tid] = e;
  __syncthreads();
  if (tid < 300) {
    float a = 0.f;
    for (int t = 0; t < 291; ++t) a += sA[t]*lnT[((size_t)b*Tn + t)*300 + tid];
    sW[tid] = a / den;
  }
  __syncthreads();
  if (tid < 300) {
    const float* w = Wv + tid*300;
    float a = 0.f;
    for (int i = 0; i < 300; ++i) a += sW[i]*w[i];
    RTP[b*300 + tid] = a + sP[tid];
    const float* w2 = Wvpt + tid*300;
    float a2 = 0.f;
    for (int i = 0; i < 300; ++i) a2 += sP[i]*w2[i];
    vpt[b*300 + tid] = a2;
  }
}

// ---- rpt = lnT + vpt (broadcast over t), bf16 pitch-320 zero-padded ----
__global__ __launch_bounds__(256)
void k_rptb(const float* __restrict__ lnT, const float* __restrict__ vpt,
            __hip_bfloat16* __restrict__ out)
{
  int idx = blockIdx.x*256 + threadIdx.x;
  if (idx >= Mn*Kp) return;
  int m = idx / Kp, d = idx - m*Kp;
  int b = m / Tn;
  float v = (d < 300) ? lnT[(size_t)m*300 + d] + vpt[b*300 + d] : 0.f;
  out[idx] = __float2bfloat16(v);
}

// ---- convert 12 square weights fp32[300][300] -> bf16[320][320] zero-padded,
//      stacked in order q1,k1,v1,m1,q2,... so [q;k;v] is a contiguous [960][320] ----
struct Wptrs { const float* p[12]; };
__global__ __launch_bounds__(256)
void k_wcvt(Wptrs wp, __hip_bfloat16* __restrict__ out)
{
  int idx = blockIdx.x*256 + threadIdx.x;
  if (idx >= 12*Kp*Kp) return;
  int mat = idx / (Kp*Kp);
  int rem = idx - mat*(Kp*Kp);
  int r = rem / Kp, c = rem - r*Kp;
  float v = (r < 300 && c < 300) ? wp.p[mat][r*300 + c] : 0.f;
  out[idx] = __float2bfloat16(v);
}

// ---- pack conv weights -> bf16 [2][256][320] zero-padded ----
__global__ __launch_bounds__(256)
void k_wpackb(const float* __restrict__ Wc1, const float* __restrict__ Wc2,
              const float* __restrict__ Wc3, const float* __restrict__ Wc4,
              __hip_bfloat16* __restrict__ out)
{
  int idx = blockIdx.x*256 + threadIdx.x;
  if (idx >= 2*256*Kp) return;
  int c  = idx % Kp;
  int rc = idx / Kp;
  int ch = rc / 256;
  int r  = rc % 256;
  float v = 0.f;
  if (r < 250 && c < 300) {
    const float* W; int kh, ro;
    if      (r < 25)  { W = Wc1; kh = 1; ro = r;      }
    else if (r < 75)  { W = Wc2; kh = 2; ro = r - 25; }
    else if (r < 150) { W = Wc3; kh = 3; ro = r - 75; }
    else              { W = Wc4; kh = 4; ro = r - 150;}
    int o = ro/kh, dh = ro%kh;
    v = W[((o*2 + ch)*kh + dh)*300 + c];
  }
  out[idx] = __float2bfloat16(v);
}

// ---- A-resident MFMA GEMM: C[m,n] = sum_k A[m,k]*W[n,k], K=320.
//      BM=64, A tile staged once in LDS; loop ntiles of 64 W-rows (W L2-resident).
//      Coalesced C store via LDS transpose (reuses W buffer). All bf16. ----
__global__ __launch_bounds__(256)
void k_ares(const ushort* __restrict__ A0, const ushort* __restrict__ A1,
            const ushort* __restrict__ W0, const ushort* __restrict__ W1,
            ushort* __restrict__ C0, ushort* __restrict__ C1,
            int ntiles, int cpitch)
{
  const ushort* A = blockIdx.z ? A1 : A0;
  const ushort* W = blockIdx.z ? W1 : W0;
  ushort*       C = blockIdx.z ? C1 : C0;
  int m0 = blockIdx.x*64;
  __shared__ alignas(16) ushort Asm[64*320];
  __shared__ alignas(16) ushort Wsm[64*320];   // doubles as transpose scratch [64][72]
  int tid = threadIdx.x;
  int lane = tid & 63, w = tid >> 6, wr = w >> 1, wc = w & 1;
  int lm = lane & 15, lk = lane >> 4;

  {  // stage A once (swizzled)
    uint4 ra[10];
    #pragma unroll
    for (int u = 0; u < 10; ++u) {
      int s = u*256 + tid; int row = s/40, kg = s%40;
      ra[u] = *(const uint4*)(A + (size_t)(m0+row)*Kp + kg*8);
    }
    #pragma unroll
    for (int u = 0; u < 10; ++u) {
      int s = u*256 + tid; int row = s/40, kg = s%40;
      int kgs = (kg & ~7) | ((kg ^ row) & 7);
      *(uint4*)&Asm[row*320 + kgs*8] = ra[u];
    }
  }
  uint4 rw[10];
  #pragma unroll
  for (int u = 0; u < 10; ++u) {
    int s = u*256 + tid; int row = s/40, kg = s%40;
    rw[u] = *(const uint4*)(W + (size_t)row*Kp + kg*8);
  }
  #pragma unroll 1
  for (int nt = 0; nt < ntiles; ++nt) {
    __syncthreads();   // Wsm free (prev transpose reads done); A staged (first iter)
    #pragma unroll
    for (int u = 0; u < 10; ++u) {
      int s = u*256 + tid; int row = s/40, kg = s%40;
      int kgs = (kg & ~7) | ((kg ^ row) & 7);
      *(uint4*)&Wsm[row*320 + kgs*8] = rw[u];
    }
    if (nt+1 < ntiles) {   // prefetch next W tile (latency hides under compute)
      #pragma unroll
      for (int u = 0; u < 10; ++u) {
        int s = u*256 + tid; int row = s/40, kg = s%40;
        rw[u] = *(const uint4*)(W + (size_t)((nt+1)*64+row)*Kp + kg*8);
      }
    }
    __syncthreads();   // Wsm ready
    f32x4 acc[2][2] = {};
    #pragma unroll
    for (int ks = 0; ks < 10; ++ks) {
      bf16x8 af[2], bfr[2];
      #pragma unroll
      for (int mf = 0; mf < 2; ++mf) {
        int r = wr*32 + mf*16 + lm;
        int kg = ks*4 + lk;
        int kgs = (kg & ~7) | ((kg ^ r) & 7);
        af[mf] = *(const bf16x8*)&Asm[r*320 + kgs*8];
      }
      #pragma unroll
      for (int nf = 0; nf < 2; ++nf) {
        int r = wc*32 + nf*16 + lm;
        int kg = ks*4 + lk;
        int kgs = (kg & ~7) | ((kg ^ r) & 7);
        bfr[nf] = *(const bf16x8*)&Wsm[r*320 + kgs*8];
      }
      #pragma unroll
      for (int mf = 0; mf < 2; ++mf)
        #pragma unroll
        for (int nf = 0; nf < 2; ++nf)
          acc[mf][nf] = __builtin_amdgcn_mfma_f32_16x16x32_bf16(af[mf], bfr[nf], acc[mf][nf], 0, 0, 0);
    }
    __syncthreads();   // done reading Wsm
    ushort* T = Wsm;   // transpose scratch [64][72]
    #pragma unroll
    for (int mf = 0; mf < 2; ++mf)
      #pragma unroll
      for (int nf = 0; nf < 2; ++nf)
        #pragma unroll
        for (int i = 0; i < 4; ++i) {
          int r = wr*32 + mf*16 + lk*4 + i;
          int c = wc*32 + nf*16 + lm;
          __hip_bfloat16 t = __float2bfloat16(acc[mf][nf][i]);
          T[r*72 + c] = *(ushort*)&t;
        }
    __syncthreads();   // Tbuf ready
    #pragma unroll
    for (int u = 0; u < 2; ++u) {
      int s = u*256 + tid; int row = s >> 3, g = s & 7;
      uint4 v = *(const uint4*)&T[row*72 + g*8];
      *(uint4*)(C + (size_t)(m0+row)*cpitch + nt*64 + g*8) = v;
    }
  }
}

// ---- MFMA flash attention on natural layout. X = [Mp][960] (Q|K|V), O = [Mp][320]. ----
__global__ __launch_bounds__(256)
void k_attn5(const ushort* __restrict__ X, ushort* __restrict__ O)
{
  int b = blockIdx.x, h = blockIdx.y, tid = threadIdx.x;
  __shared__ alignas(16) ushort Ks[320*40];   // K rows, pitch 40
  __shared__ alignas(16) ushort Vt[32*328];   // V^T rows d, pitch 328
  __shared__ alignas(16) ushort Ps[64*168];   // P rows q (half-j), pitch 168
  const size_t rbase = (size_t)b*Tn*960;
  const int hq = h*30;
  for (int i = tid; i < 320*20; i += 256) {   // K staging (cols>=30 and rows>=Tn zeroed)
    int r = i/20, c2 = i%20;
    uint v = 0u;
    if (r < Tn && c2 < 15) v = *(const uint*)(X + rbase + (size_t)r*960 + 320 + hq + 2*c2);
    *(uint*)&Ks[r*40 + 2*c2] = v;
  }
  for (int i = tid; i < 320*16; i += 256) {   // V staging transposed
    int j = i >> 4, c2 = i & 15;
    if (c2 < 15) {
      uint v = (j < Tn) ? *(const uint*)(X + rbase + (size_t)j*960 + 640 + hq + 2*c2) : 0u;
      Vt[(2*c2)*328 + j]   = (ushort)(v & 0xffffu);
      Vt[(2*c2+1)*328 + j] = (ushort)(v >> 16);
    } else {
      Vt[30*328 + j] = 0; Vt[31*328 + j] = 0;
    }
  }
  __syncthreads();
  int lane = tid & 63, w = tid >> 6;
  int lm = lane & 15, lk = lane >> 4;
  int qloc = w*16 + lm;
  const float scale = 0.31622776601683794f;   // 1/sqrt(H)
  #pragma unroll 1
  for (int qt = 0; qt < 5; ++qt) {
    int qrow = qt*64 + w*16 + lm;             // may exceed Tn; masked at store
    union { uint u[4]; bf16x8 v; } qq;
    {
      const uint* qp = (const uint*)(X + rbase + (size_t)qrow*960 + hq + lk*8);
      qq.u[0]=qp[0]; qq.u[1]=qp[1]; qq.u[2]=qp[2]; qq.u[3]=qp[3];
    }
    bf16x8 qf = qq.v;
    float rsum = 0.f;
    f32x4 oacc[2] = {};
    #pragma unroll 1
    for (int jh = 0; jh < 2; ++jh) {
      #pragma unroll
      for (int jtl = 0; jtl < 10; ++jtl) {
        int jt = jh*10 + jtl;
        bf16x8 kf = *(const bf16x8*)&Ks[(jt*16+lm)*40 + lk*8];
        f32x4 s = {};
        s = __builtin_amdgcn_mfma_f32_16x16x32_bf16(kf, qf, s, 0, 0, 0);
        union { ushort u[4]; uint2 v2; } pk;
        #pragma unroll
        for (int i2 = 0; i2 < 4; ++i2) {
          int j = jt*16 + lk*4 + i2;
          float p = (j < Tn) ? __expf(s[i2]*scale) : 0.f;
          rsum += p;
          __hip_bfloat16 t = __float2bfloat16(p);
          pk.u[i2] = *(ushort*)&t;
        }
        *(uint2*)&Ps[qloc*168 + jtl*16 + lk*4] = pk.v2;
      }
      #pragma unroll
      for (int ktl = 0; ktl < 5; ++ktl) {
        bf16x8 pf = *(const bf16x8*)&Ps[qloc*168 + ktl*32 + lk*8];
        int jb = jh*160 + ktl*32 + lk*8;
        #pragma unroll
        for (int nf = 0; nf < 2; ++nf) {
          bf16x8 vf = *(const bf16x8*)&Vt[(nf*16+lm)*328 + jb];
          oacc[nf] = __builtin_amdgcn_mfma_f32_16x16x32_bf16(pf, vf, oacc[nf], 0, 0, 0);
        }
      }
    }
    rsum += __shfl_xor(rsum, 16, 64);
    rsum += __shfl_xor(rsum, 32, 64);
    float inv[4];
    #pragma unroll
    for (int i2 = 0; i2 < 4; ++i2) inv[i2] = 1.f / __shfl(rsum, lk*4 + i2, 64);
    #pragma unroll
    for (int nf = 0; nf < 2; ++nf) {
      int d = nf*16 + lm;
      if (d < 30) {
        #pragma unroll
        for (int i2 = 0; i2 < 4; ++i2) {
          int q = qt*64 + w*16 + lk*4 + i2;
          if (q < Tn) {
            __hip_bfloat16 t = __float2bfloat16(oacc[nf][i2]*inv[i2]);
            O[((size_t)b*Tn + q)*Kp + hq + d] = *(ushort*)&t;
          }
        }
      }
    }
  }
}

// ---- conv head reduce: G0,G1 bf16 pitch 256 ----
__global__ __launch_bounds__(256)
void k_convred2(const ushort* __restrict__ G0, const ushort* __restrict__ G1,
                const float* __restrict__ bc1, const float* __restrict__ bc2,
                const float* __restrict__ bc3, const float* __restrict__ bc4,
                float* __restrict__ out100)
{
  int b = blockIdx.x, head = blockIdx.y;
  int kh  = head + 1;
  int off = (head == 0) ? 0 : (head == 1) ? 25 : (head == 2) ? 75 : 150;
  const float* bc = (head == 0) ? bc1 : (head == 1) ? bc2 : (head == 2) ? bc3 : bc4;
  int ncol = 25*kh;
  int ncp  = ncol | 1;
  int L = Tn - kh + 1;
  __shared__ float S[67*101];
  int tid = threadIdx.x, lane = tid & 63;
  float mx[7];
  #pragma unroll
  for (int u = 0; u < 7; ++u) mx[u] = -1e30f;
  for (int l0 = 0; l0 < L; l0 += 64) {
    int nrows = min(64 + kh - 1, Tn - l0);
    __syncthreads();
    for (int i = tid; i < nrows*ncol; i += 256) {
      int r = i / ncol, c = i % ncol;
      size_t g = (size_t)(b*Tn + l0 + r)*256 + off + c;
      __hip_bfloat16 a = *(const __hip_bfloat16*)&G0[g];
      __hip_bfloat16 d = *(const __hip_bfloat16*)&G1[g];
      S[r*ncp + c] = __bfloat162float(a) + __bfloat162float(d);
    }
    __syncthreads();
    int lmax = min(64, L - l0);
    #pragma unroll
    for (int u = 0; u < 7; ++u) {
      int o = (tid >> 6) + u*4;
      int dl = lane;
      if (o < 25 && dl < lmax) {
        float s = bc[o];
        for (int dh = 0; dh < kh; ++dh)
          s += S[(dl+dh)*ncp + o*kh + dh];
        mx[u] = fmaxf(mx[u], leaky(s));
      }
    }
  }
  #pragma unroll
  for (int u = 0; u < 7; ++u) {
    float v = mx[u];
    #pragma unroll
    for (int ofs = 32; ofs > 0; ofs >>= 1) v = fmaxf(v, __shfl_down(v, ofs, 64));
    int o = (tid >> 6) + u*4;
    if (lane == 0 && o < 25)
      out100[b*100 + head*25 + o] = v;
  }
}

// ---- final head ----
__global__ __launch_bounds__(320)
void k_final(const float* __restrict__ RTP, const float* __restrict__ out100,
             const float* __restrict__ Wlin, const float* __restrict__ blin,
             const float* __restrict__ Wlast, const float* __restrict__ blast,
             float* __restrict__ Y)
{
  int b = blockIdx.x, tid = threadIdx.x;
  __shared__ float cat[600];
  __shared__ float s100[100];
  __shared__ float red[5];
  if (tid < 100) s100[tid] = out100[b*100 + tid];
  if (tid < 300) cat[tid] = RTP[b*300 + tid];
  __syncthreads();
  if (tid < 300) {
    const float* w = Wlin + tid*100;
    float a = blin[tid];
    for (int j = 0; j < 100; ++j) a += s100[j]*w[j];
    cat[300 + tid] = leaky(a);
  }
  __syncthreads();
  for (int c = 0; c < 2; ++c) {
    float a = 0.f;
    for (int i = tid; i < 600; i += 320) a += cat[i]*Wlast[c*600 + i];
    a = blockSum<320>(a, red);
    if (tid == 0) Y[b*2 + c] = a + blast[c];
  }
}

extern "C" void kernel_launch(void* const* d_in, const int* in_sizes, int n_in,
                              void* d_out, int out_size, void* d_ws, size_t ws_size,
                              hipStream_t stream)
{
  (void)in_sizes; (void)n_in; (void)out_size; (void)ws_size;
  const float* x1    = (const float*)d_in[0];
  const float* x2    = (const float*)d_in[1];
  const float* Wimg  = (const float*)d_in[2];
  const float* bimg  = (const float*)d_in[3];
  const float* g1    = (const float*)d_in[4];
  const float* be1   = (const float*)d_in[5];
  const float* g2    = (const float*)d_in[6];
  const float* be2   = (const float*)d_in[7];
  const float* Wq_tp = (const float*)d_in[8];
  const float* Wk_tp = (const float*)d_in[9];
  const float* Wv_tp = (const float*)d_in[10];
  const float* Wv_pt = (const float*)d_in[13];   // Wq_pt/Wk_pt dead (softmax over size-1)
  const float* Wc1 = (const float*)d_in[26];
  const float* Wc2 = (const float*)d_in[27];
  const float* Wc3 = (const float*)d_in[28];
  const float* Wc4 = (const float*)d_in[29];
  const float* bc1 = (const float*)d_in[30];
  const float* bc2 = (const float*)d_in[31];
  const float* bc3 = (const float*)d_in[32];
  const float* bc4 = (const float*)d_in[33];
  const float* Wlin  = (const float*)d_in[34];
  const float* blin  = (const float*)d_in[35];
  const float* Wlast = (const float*)d_in[36];
  const float* blast = (const float*)d_in[37];

  char* base = (char*)d_ws;
  float* lnP    = (float*)(base + 0);
  float* RTP    = (float*)(base + 76800);
  float* vpt    = (float*)(base + 153600);
  float* out100 = (float*)(base + 230400);
  float* lnTf   = (float*)(base + 262144);            // fp32 lnT (dead before conv)
  ushort* G0    = (ushort*)(base + 262144);           // alias lnTf region (bf16 [Mp][256])
  ushort* G1    = (ushort*)(base + 262144 + 9568256);
  ushort* X960  = (ushort*)(base + 22610944);         // [Mp][960] bf16
  ushort* P0    = (ushort*)(base + 58491904);         // [Mp][320] bf16 (layer input)
  ushort* P1    = (ushort*)(base + 70452224);         // rpt (conv A)
  ushort* P2    = (ushort*)(base + 82412544);         // attn out
  ushort* Wb    = (ushort*)(base + 94372864);         // 12 x [320][320] bf16
  ushort* Wpb   = (ushort*)(base + 96830464);         // 2 x [256][320] bf16
  const int WS = Kp*Kp;  // 102400

  // prologue (fp32)
  k_img_lnp<<<Bn, 256, 0, stream>>>(x2, Wimg, bimg, g2, be2, lnP);
  k_lnT<<<Bn, 1024, 0, stream>>>(x1, g1, be1, lnTf, (__hip_bfloat16*)P0);
  k_tp<<<Bn, 320, 0, stream>>>(lnP, lnTf, Wq_tp, Wk_tp, Wv_tp, Wv_pt, RTP, vpt);
  k_rptb<<<(Mn*Kp + 255)/256, 256, 0, stream>>>(lnTf, vpt, (__hip_bfloat16*)P1);

  Wptrs wp;
  for (int i = 0; i < 12; ++i) wp.p[i] = (const float*)d_in[14 + i];
  k_wcvt<<<(12*WS + 255)/256, 256, 0, stream>>>(wp, (__hip_bfloat16*)Wb);
  k_wpackb<<<(2*256*Kp + 255)/256, 256, 0, stream>>>(Wc1, Wc2, Wc3, Wc4, (__hip_bfloat16*)Wpb);

  dim3 g1d(Mp/64, 1, 1), g2d(Mp/64, 1, 2), gat(Bn, Hn);
  for (int l = 0; l < 3; ++l) {
    const ushort* Wqkv = Wb + (size_t)l*4*WS;      // [960][320] stacked q,k,v
    const ushort* Wm   = Wb + ((size_t)l*4+3)*WS;  // [320][320]
    k_ares<<<g1d, 256, 0, stream>>>(P0, P0, Wqkv, Wqkv, X960, X960, 15, 960);
    k_attn5<<<gat, 256, 0, stream>>>(X960, P2);
    k_ares<<<g1d, 256, 0, stream>>>(P2, P2, Wm, Wm, P0, P0, 5, 320);
  }
  // conv GEMMs: z0: G0 = rpt(P1) @ Wpb0.T ; z1: G1 = a3(P0) @ Wpb1.T
  k_ares<<<g2d, 256, 0, stream>>>(P1, P0, Wpb, Wpb + 256*Kp, G0, G1, 4, 256);
  k_convred2<<<dim3(Bn,4), 256, 0, stream>>>(G0, G1, bc1, bc2, bc3, bc4, out100);
  k_final<<<Bn, 320, 0, stream>>>(RTP, out100, Wlin, blin, Wlast, blast, (float*)d_out);
}

// Round 7
// 860.753 us; speedup vs baseline: 3.5402x; 1.0785x over previous
//
#include <hip/hip_runtime.h>
#include <hip/hip_bf16.h>
#include <math.h>

#define Bn 64
#define Tn 291
#define Dn 300
#define Hn 10
#define Mn (Bn*Tn)   // 18624
#define Mp 18688     // 146*128 padded rows
#define Kp 320       // padded K / activation pitch

typedef __bf16 bf16x8 __attribute__((ext_vector_type(8)));
typedef float f32x4 __attribute__((ext_vector_type(4)));

static __device__ __forceinline__ float leaky(float x){ return x >= 0.f ? x : 0.01f*x; }

template<int NT>
static __device__ __forceinline__ float blockSum(float v, float* red){
  __syncthreads();
  int lane = threadIdx.x & 63, wid = threadIdx.x >> 6;
  #pragma unroll
  for (int o = 32; o > 0; o >>= 1) v += __shfl_down(v, o, 64);
  if (lane == 0) red[wid] = v;
  __syncthreads();
  if (threadIdx.x == 0) {
    float s = red[0];
    #pragma unroll
    for (int w = 1; w < NT/64; ++w) s += red[w];
    red[0] = s;
  }
  __syncthreads();
  return red[0];
}

template<int NT>
static __device__ __forceinline__ float blockMax(float v, float* red){
  __syncthreads();
  int lane = threadIdx.x & 63, wid = threadIdx.x >> 6;
  #pragma unroll
  for (int o = 32; o > 0; o >>= 1) v = fmaxf(v, __shfl_down(v, o, 64));
  if (lane == 0) red[wid] = v;
  __syncthreads();
  if (threadIdx.x == 0) {
    float s = red[0];
    #pragma unroll
    for (int w = 1; w < NT/64; ++w) s = fmaxf(s, red[w]);
    red[0] = s;
  }
  __syncthreads();
  return red[0];
}

// ---- image branch ----
__global__ __launch_bounds__(256)
void k_img_lnp(const float* __restrict__ x2, const float* __restrict__ Wimg,
               const float* __restrict__ bimg, const float* __restrict__ g2,
               const float* __restrict__ be2, float* __restrict__ lnP)
{
  int b = blockIdx.x, tid = threadIdx.x;
  __shared__ float sx[1000];
  __shared__ float sy[300];
  __shared__ float red[4];
  for (int i = tid; i < 1000; i += 256) sx[i] = x2[b*1000 + i];
  __syncthreads();
  for (int j = tid; j < 300; j += 256) {
    const float* w = Wimg + j*1000;
    float a = 0.f;
    for (int i = 0; i < 1000; ++i) a += sx[i]*w[i];
    sy[j] = leaky(a + bimg[j]);
  }
  __syncthreads();
  float s = 0.f, ss = 0.f;
  for (int j = tid; j < 300; j += 256) { float v = sy[j]; s += v; ss += v*v; }
  float tot  = blockSum<256>(s, red);
  float tot2 = blockSum<256>(ss, red);
  float mu   = tot * (1.f/300.f);
  float var  = tot2 * (1.f/300.f) - mu*mu;
  float rstd = rsqrtf(var + 1e-5f);
  for (int j = tid; j < 300; j += 256)
    lnP[b*300 + j] = (sy[j]-mu)*rstd*g2[j] + be2[j];
}

// ---- lnT: LayerNorm over (291,300); fp32 (pitch 300) + bf16 (pitch 320, zero-padded) ----
__global__ __launch_bounds__(1024)
void k_lnT(const float* __restrict__ x1, const float* __restrict__ g1,
           const float* __restrict__ be1, float* __restrict__ outf,
           __hip_bfloat16* __restrict__ outb)
{
  int b = blockIdx.x, tid = threadIdx.x;
  __shared__ float red[16];
  const float4* xb = (const float4*)(x1 + (size_t)b*87300);
  const float4* g4 = (const float4*)g1;
  const float4* b4 = (const float4*)be1;
  float4* o4 = (float4*)(outf + (size_t)b*87300);
  float s = 0.f, ss = 0.f;
  for (int i = tid; i < 21825; i += 1024) {
    float4 v = xb[i];
    s  += v.x+v.y+v.z+v.w;
    ss += v.x*v.x+v.y*v.y+v.z*v.z+v.w*v.w;
  }
  float tot  = blockSum<1024>(s, red);
  float tot2 = blockSum<1024>(ss, red);
  float mu   = tot / 87300.f;
  float var  = tot2 / 87300.f - mu*mu;
  float rstd = rsqrtf(var + 1e-5f);
  for (int i = tid; i < 21825; i += 1024) {
    float4 v = xb[i], g = g4[i], be = b4[i], o;
    o.x = (v.x-mu)*rstd*g.x + be.x;
    o.y = (v.y-mu)*rstd*g.y + be.y;
    o.z = (v.z-mu)*rstd*g.z + be.z;
    o.w = (v.w-mu)*rstd*g.w + be.w;
    o4[i] = o;
  }
  const float* xs = x1 + (size_t)b*87300;
  for (int e = tid; e < Tn*Dn; e += 1024) {
    int t = e/300;
    float x = xs[e];
    outb[(size_t)(b*Tn+t)*Kp + (e - t*300)] = __float2bfloat16((x-mu)*rstd*g1[e] + be1[e]);
  }
  for (int e = tid; e < Tn*20; e += 1024) {
    int t = e/20, d = 300 + e%20;
    outb[(size_t)(b*Tn+t)*Kp + d] = __float2bfloat16(0.f);
  }
}

// ---- T->P cross attention (single query) + v for P->T branch ----
__global__ __launch_bounds__(320)
void k_tp(const float* __restrict__ lnP, const float* __restrict__ lnT,
          const float* __restrict__ Wq, const float* __restrict__ Wk,
          const float* __restrict__ Wv, const float* __restrict__ Wvpt,
          float* __restrict__ RTP, float* __restrict__ vpt)
{
  int b = blockIdx.x, tid = threadIdx.x;
  __shared__ float sP[300], sQ[300], sM[300], sA[291], sW[300], red[5];
  if (tid < 300) sP[tid] = lnP[b*300 + tid];
  __syncthreads();
  if (tid < 300) {
    const float* w = Wq + tid*300;
    float a = 0.f;
    for (int i = 0; i < 300; ++i) a += sP[i]*w[i];
    sQ[tid] = a;
  }
  __syncthreads();
  if (tid < 300) {
    float a = 0.f;
    for (int j = 0; j < 300; ++j) a += sQ[j]*Wk[j*300 + tid];
    sM[tid] = a;
  }
  __syncthreads();
  float sc = -1e30f;
  if (tid < 291) {
    const float* r = lnT + ((size_t)b*Tn + tid)*300;
    float a = 0.f;
    for (int i = 0; i < 300; ++i) a += r[i]*sM[i];
    sc = a;
  }
  float mx  = blockMax<320>(sc, red);
  float e   = (tid < 291) ? __expf(sc - mx) : 0.f;
  float den = blockSum<320>(e, red);
  if (tid < 291) sA[tid] = e;
  __syncthreads();
  if (tid < 300) {
    float a = 0.f;
    for (int t = 0; t < 291; ++t) a += sA[t]*lnT[((size_t)b*Tn + t)*300 + tid];
    sW[tid] = a / den;
  }
  __syncthreads();
  if (tid < 300) {
    const float* w = Wv + tid*300;
    float a = 0.f;
    for (int i = 0; i < 300; ++i) a += sW[i]*w[i];
    RTP[b*300 + tid] = a + sP[tid];
    const float* w2 = Wvpt + tid*300;
    float a2 = 0.f;
    for (int i = 0; i < 300; ++i) a2 += sP[i]*w2[i];
    vpt[b*300 + tid] = a2;
  }
}

// ---- rpt = lnT + vpt (broadcast over t), bf16 pitch-320 zero-padded ----
__global__ __launch_bounds__(256)
void k_rptb(const float* __restrict__ lnT, const float* __restrict__ vpt,
            __hip_bfloat16* __restrict__ out)
{
  int idx = blockIdx.x*256 + threadIdx.x;
  if (idx >= Mn*Kp) return;
  int m = idx / Kp, d = idx - m*Kp;
  int b = m / Tn;
  float v = (d < 300) ? lnT[(size_t)m*300 + d] + vpt[b*300 + d] : 0.f;
  out[idx] = __float2bfloat16(v);
}

// ---- convert 12 square weights fp32[300][300] -> bf16[320][320] zero-padded,
//      stacked q1,k1,v1,m1,q2,... so [q;k;v] is contiguous [960][320] ----
struct Wptrs { const float* p[12]; };
__global__ __launch_bounds__(256)
void k_wcvt(Wptrs wp, __hip_bfloat16* __restrict__ out)
{
  int idx = blockIdx.x*256 + threadIdx.x;
  if (idx >= 12*Kp*Kp) return;
  int mat = idx / (Kp*Kp);
  int rem = idx - mat*(Kp*Kp);
  int r = rem / Kp, c = rem - r*Kp;
  float v = (r < 300 && c < 300) ? wp.p[mat][r*300 + c] : 0.f;
  out[idx] = __float2bfloat16(v);
}

// ---- pack conv weights -> bf16 [2][256][320] zero-padded ----
__global__ __launch_bounds__(256)
void k_wpackb(const float* __restrict__ Wc1, const float* __restrict__ Wc2,
              const float* __restrict__ Wc3, const float* __restrict__ Wc4,
              __hip_bfloat16* __restrict__ out)
{
  int idx = blockIdx.x*256 + threadIdx.x;
  if (idx >= 2*256*Kp) return;
  int c  = idx % Kp;
  int rc = idx / Kp;
  int ch = rc / 256;
  int r  = rc % 256;
  float v = 0.f;
  if (r < 250 && c < 300) {
    const float* W; int kh, ro;
    if      (r < 25)  { W = Wc1; kh = 1; ro = r;      }
    else if (r < 75)  { W = Wc2; kh = 2; ro = r - 25; }
    else if (r < 150) { W = Wc3; kh = 3; ro = r - 75; }
    else              { W = Wc4; kh = 4; ro = r - 150;}
    int o = ro/kh, dh = ro%kh;
    v = W[((o*2 + ch)*kh + dh)*300 + c];
  }
  out[idx] = __float2bfloat16(v);
}

// ---- MFMA GEMM v3: C[m,n] = sum_k A[m,k]*W[n,k], K=320. 128x64 tile, 4 waves,
//      5 K-tiles of 64, double-buffered LDS + XOR swizzle (0 conflicts, r4-verified),
//      bijective XCD-chunk swizzle (n fast within a chunk -> A panel stays in one L2),
//      coalesced bf16 C store via LDS transpose. ----
__global__ __launch_bounds__(256)
void k_gemm3(const ushort* __restrict__ A0, const ushort* __restrict__ A1,
             const ushort* __restrict__ W0, const ushort* __restrict__ W1,
             ushort* __restrict__ C0, ushort* __restrict__ C1,
             int nn, int cpitch)
{
  const ushort* A = blockIdx.z ? A1 : A0;
  const ushort* W = blockIdx.z ? W1 : W0;
  ushort*       C = blockIdx.z ? C1 : C0;
  // bijective XCD swizzle (m204): contiguous wgid chunk per XCD
  int total = gridDim.x;
  int bid = blockIdx.x;
  int q = total >> 3, r = total & 7;
  int xcd = bid & 7, idx = bid >> 3;
  int wgid = (xcd < r ? xcd*(q+1) : r*(q+1) + (xcd-r)*q) + idx;
  int m0 = (wgid / nn) * 128, n0 = (wgid % nn) * 64;

  __shared__ alignas(16) ushort As[2][128*64];
  __shared__ alignas(16) ushort Bs[2][64*64];
  int tid = threadIdx.x;
  int lane = tid & 63, w = tid >> 6, wr = w >> 1, wc = w & 1;
  int lm = lane & 15, lk = lane >> 4;
  f32x4 acc[4][2] = {};
  uint4 ra[4], rw[2];

  auto loadregs = [&](int kt){
    #pragma unroll
    for (int u = 0; u < 4; ++u) {
      int s = tid + u*256; int row = s >> 3, kg = s & 7;
      ra[u] = *(const uint4*)(A + (size_t)(m0+row)*Kp + kt*64 + kg*8);
    }
    #pragma unroll
    for (int u = 0; u < 2; ++u) {
      int s = tid + u*256; int row = s >> 3, kg = s & 7;
      rw[u] = *(const uint4*)(W + (size_t)(n0+row)*Kp + kt*64 + kg*8);
    }
  };
  auto writeLDS = [&](int buf){
    #pragma unroll
    for (int u = 0; u < 4; ++u) {
      int s = tid + u*256; int row = s >> 3, kg = s & 7;
      *(uint4*)&As[buf][row*64 + ((kg ^ (row&7)) << 3)] = ra[u];
    }
    #pragma unroll
    for (int u = 0; u < 2; ++u) {
      int s = tid + u*256; int row = s >> 3, kg = s & 7;
      *(uint4*)&Bs[buf][row*64 + ((kg ^ (row&7)) << 3)] = rw[u];
    }
  };
  auto compute = [&](int buf){
    #pragma unroll
    for (int s = 0; s < 2; ++s) {
      bf16x8 af[4], bfr[2];
      int kg = s*4 + lk;
      #pragma unroll
      for (int mf = 0; mf < 4; ++mf) {
        int rr = wr*64 + mf*16 + lm;
        af[mf] = *(const bf16x8*)&As[buf][rr*64 + ((kg ^ (rr&7)) << 3)];
      }
      #pragma unroll
      for (int nf = 0; nf < 2; ++nf) {
        int rr = wc*32 + nf*16 + lm;
        bfr[nf] = *(const bf16x8*)&Bs[buf][rr*64 + ((kg ^ (rr&7)) << 3)];
      }
      #pragma unroll
      for (int mf = 0; mf < 4; ++mf)
        #pragma unroll
        for (int nf = 0; nf < 2; ++nf)
          acc[mf][nf] = __builtin_amdgcn_mfma_f32_16x16x32_bf16(af[mf], bfr[nf], acc[mf][nf], 0, 0, 0);
    }
  };

  loadregs(0); writeLDS(0);
  __syncthreads();
  #pragma unroll 1
  for (int kt = 0; kt < 5; ++kt) {
    if (kt < 4) loadregs(kt+1);
    compute(kt & 1);
    if (kt < 4) {
      __syncthreads();
      writeLDS((kt+1) & 1);
      __syncthreads();
    }
  }
  // coalesced store: acc -> LDS transpose (reuse As, 128x72 ushort) -> uint4 stores
  __syncthreads();
  ushort* T = &As[0][0];
  #pragma unroll
  for (int mf = 0; mf < 4; ++mf)
    #pragma unroll
    for (int nf = 0; nf < 2; ++nf)
      #pragma unroll
      for (int i = 0; i < 4; ++i) {
        int rr = wr*64 + mf*16 + lk*4 + i;
        int cc = wc*32 + nf*16 + lm;
        __hip_bfloat16 t = __float2bfloat16(acc[mf][nf][i]);
        T[rr*72 + cc] = *(ushort*)&t;
      }
  __syncthreads();
  #pragma unroll
  for (int u = 0; u < 4; ++u) {
    int s = tid + u*256; int row = s >> 3, g = s & 7;
    uint4 v = *(const uint4*)&T[row*72 + g*8];
    *(uint4*)(C + (size_t)(m0+row)*cpitch + n0 + g*8) = v;
  }
}

// ---- MFMA flash attention on natural layout. X = [Mp][960] (Q|K|V), O = [Mp][320]. ----
__global__ __launch_bounds__(256)
void k_attn5(const ushort* __restrict__ X, ushort* __restrict__ O)
{
  int b = blockIdx.x, h = blockIdx.y, tid = threadIdx.x;
  __shared__ alignas(16) ushort Ks[320*40];   // K rows, pitch 40
  __shared__ alignas(16) ushort Vt[32*328];   // V^T rows d, pitch 328
  __shared__ alignas(16) ushort Ps[64*168];   // P rows q (half-j), pitch 168
  const size_t rbase = (size_t)b*Tn*960;
  const int hq = h*30;
  for (int i = tid; i < 320*20; i += 256) {
    int r = i/20, c2 = i%20;
    uint v = 0u;
    if (r < Tn && c2 < 15) v = *(const uint*)(X + rbase + (size_t)r*960 + 320 + hq + 2*c2);
    *(uint*)&Ks[r*40 + 2*c2] = v;
  }
  for (int i = tid; i < 320*16; i += 256) {
    int j = i >> 4, c2 = i & 15;
    if (c2 < 15) {
      uint v = (j < Tn) ? *(const uint*)(X + rbase + (size_t)j*960 + 640 + hq + 2*c2) : 0u;
      Vt[(2*c2)*328 + j]   = (ushort)(v & 0xffffu);
      Vt[(2*c2+1)*328 + j] = (ushort)(v >> 16);
    } else {
      Vt[30*328 + j] = 0; Vt[31*328 + j] = 0;
    }
  }
  __syncthreads();
  int lane = tid & 63, w = tid >> 6;
  int lm = lane & 15, lk = lane >> 4;
  int qloc = w*16 + lm;
  const float scale = 0.31622776601683794f;   // 1/sqrt(H)
  #pragma unroll 1
  for (int qt = 0; qt < 5; ++qt) {
    int qrow = qt*64 + w*16 + lm;             // may exceed Tn; masked at store
    union { uint u[4]; bf16x8 v; } qq;
    {
      const uint* qp = (const uint*)(X + rbase + (size_t)qrow*960 + hq + lk*8);
      qq.u[0]=qp[0]; qq.u[1]=qp[1]; qq.u[2]=qp[2]; qq.u[3]=qp[3];
    }
    bf16x8 qf = qq.v;
    float rsum = 0.f;
    f32x4 oacc[2] = {};
    #pragma unroll 1
    for (int jh = 0; jh < 2; ++jh) {
      #pragma unroll
      for (int jtl = 0; jtl < 10; ++jtl) {
        int jt = jh*10 + jtl;
        bf16x8 kf = *(const bf16x8*)&Ks[(jt*16+lm)*40 + lk*8];
        f32x4 s = {};
        s = __builtin_amdgcn_mfma_f32_16x16x32_bf16(kf, qf, s, 0, 0, 0);
        union { ushort u[4]; uint2 v2; } pk;
        #pragma unroll
        for (int i2 = 0; i2 < 4; ++i2) {
          int j = jt*16 + lk*4 + i2;
          float p = (j < Tn) ? __expf(s[i2]*scale) : 0.f;
          rsum += p;
          __hip_bfloat16 t = __float2bfloat16(p);
          pk.u[i2] = *(ushort*)&t;
        }
        *(uint2*)&Ps[qloc*168 + jtl*16 + lk*4] = pk.v2;
      }
      #pragma unroll
      for (int ktl = 0; ktl < 5; ++ktl) {
        bf16x8 pf = *(const bf16x8*)&Ps[qloc*168 + ktl*32 + lk*8];
        int jb = jh*160 + ktl*32 + lk*8;
        #pragma unroll
        for (int nf = 0; nf < 2; ++nf) {
          bf16x8 vf = *(const bf16x8*)&Vt[(nf*16+lm)*328 + jb];
          oacc[nf] = __builtin_amdgcn_mfma_f32_16x16x32_bf16(pf, vf, oacc[nf], 0, 0, 0);
        }
      }
    }
    rsum += __shfl_xor(rsum, 16, 64);
    rsum += __shfl_xor(rsum, 32, 64);
    float inv[4];
    #pragma unroll
    for (int i2 = 0; i2 < 4; ++i2) inv[i2] = 1.f / __shfl(rsum, lk*4 + i2, 64);
    #pragma unroll
    for (int nf = 0; nf < 2; ++nf) {
      int d = nf*16 + lm;
      if (d < 30) {
        #pragma unroll
        for (int i2 = 0; i2 < 4; ++i2) {
          int qrw = qt*64 + w*16 + lk*4 + i2;
          if (qrw < Tn) {
            __hip_bfloat16 t = __float2bfloat16(oacc[nf][i2]*inv[i2]);
            O[((size_t)b*Tn + qrw)*Kp + hq + d] = *(ushort*)&t;
          }
        }
      }
    }
  }
}

// ---- conv head reduce: G0,G1 bf16 pitch 256 ----
__global__ __launch_bounds__(256)
void k_convred2(const ushort* __restrict__ G0, const ushort* __restrict__ G1,
                const float* __restrict__ bc1, const float* __restrict__ bc2,
                const float* __restrict__ bc3, const float* __restrict__ bc4,
                float* __restrict__ out100)
{
  int b = blockIdx.x, head = blockIdx.y;
  int kh  = head + 1;
  int off = (head == 0) ? 0 : (head == 1) ? 25 : (head == 2) ? 75 : 150;
  const float* bc = (head == 0) ? bc1 : (head == 1) ? bc2 : (head == 2) ? bc3 : bc4;
  int ncol = 25*kh;
  int ncp  = ncol | 1;
  int L = Tn - kh + 1;
  __shared__ float S[67*101];
  int tid = threadIdx.x, lane = tid & 63;
  float mx[7];
  #pragma unroll
  for (int u = 0; u < 7; ++u) mx[u] = -1e30f;
  for (int l0 = 0; l0 < L; l0 += 64) {
    int nrows = min(64 + kh - 1, Tn - l0);
    __syncthreads();
    for (int i = tid; i < nrows*ncol; i += 256) {
      int r = i / ncol, c = i % ncol;
      size_t g = (size_t)(b*Tn + l0 + r)*256 + off + c;
      __hip_bfloat16 a = *(const __hip_bfloat16*)&G0[g];
      __hip_bfloat16 d = *(const __hip_bfloat16*)&G1[g];
      S[r*ncp + c] = __bfloat162float(a) + __bfloat162float(d);
    }
    __syncthreads();
    int lmax = min(64, L - l0);
    #pragma unroll
    for (int u = 0; u < 7; ++u) {
      int o = (tid >> 6) + u*4;
      int dl = lane;
      if (o < 25 && dl < lmax) {
        float s = bc[o];
        for (int dh = 0; dh < kh; ++dh)
          s += S[(dl+dh)*ncp + o*kh + dh];
        mx[u] = fmaxf(mx[u], leaky(s));
      }
    }
  }
  #pragma unroll
  for (int u = 0; u < 7; ++u) {
    float v = mx[u];
    #pragma unroll
    for (int ofs = 32; ofs > 0; ofs >>= 1) v = fmaxf(v, __shfl_down(v, ofs, 64));
    int o = (tid >> 6) + u*4;
    if (lane == 0 && o < 25)
      out100[b*100 + head*25 + o] = v;
  }
}

// ---- final head ----
__global__ __launch_bounds__(320)
void k_final(const float* __restrict__ RTP, const float* __restrict__ out100,
             const float* __restrict__ Wlin, const float* __restrict__ blin,
             const float* __restrict__ Wlast, const float* __restrict__ blast,
             float* __restrict__ Y)
{
  int b = blockIdx.x, tid = threadIdx.x;
  __shared__ float cat[600];
  __shared__ float s100[100];
  __shared__ float red[5];
  if (tid < 100) s100[tid] = out100[b*100 + tid];
  if (tid < 300) cat[tid] = RTP[b*300 + tid];
  __syncthreads();
  if (tid < 300) {
    const float* w = Wlin + tid*100;
    float a = blin[tid];
    for (int j = 0; j < 100; ++j) a += s100[j]*w[j];
    cat[300 + tid] = leaky(a);
  }
  __syncthreads();
  for (int c = 0; c < 2; ++c) {
    float a = 0.f;
    for (int i = tid; i < 600; i += 320) a += cat[i]*Wlast[c*600 + i];
    a = blockSum<320>(a, red);
    if (tid == 0) Y[b*2 + c] = a + blast[c];
  }
}

extern "C" void kernel_launch(void* const* d_in, const int* in_sizes, int n_in,
                              void* d_out, int out_size, void* d_ws, size_t ws_size,
                              hipStream_t stream)
{
  (void)in_sizes; (void)n_in; (void)out_size; (void)ws_size;
  const float* x1    = (const float*)d_in[0];
  const float* x2    = (const float*)d_in[1];
  const float* Wimg  = (const float*)d_in[2];
  const float* bimg  = (const float*)d_in[3];
  const float* g1    = (const float*)d_in[4];
  const float* be1   = (const float*)d_in[5];
  const float* g2    = (const float*)d_in[6];
  const float* be2   = (const float*)d_in[7];
  const float* Wq_tp = (const float*)d_in[8];
  const float* Wk_tp = (const float*)d_in[9];
  const float* Wv_tp = (const float*)d_in[10];
  const float* Wv_pt = (const float*)d_in[13];   // Wq_pt/Wk_pt dead (softmax over size-1)
  const float* Wc1 = (const float*)d_in[26];
  const float* Wc2 = (const float*)d_in[27];
  const float* Wc3 = (const float*)d_in[28];
  const float* Wc4 = (const float*)d_in[29];
  const float* bc1 = (const float*)d_in[30];
  const float* bc2 = (const float*)d_in[31];
  const float* bc3 = (const float*)d_in[32];
  const float* bc4 = (const float*)d_in[33];
  const float* Wlin  = (const float*)d_in[34];
  const float* blin  = (const float*)d_in[35];
  const float* Wlast = (const float*)d_in[36];
  const float* blast = (const float*)d_in[37];

  char* base = (char*)d_ws;
  float* lnP    = (float*)(base + 0);
  float* RTP    = (float*)(base + 76800);
  float* vpt    = (float*)(base + 153600);
  float* out100 = (float*)(base + 230400);
  float* lnTf   = (float*)(base + 262144);            // fp32 lnT (dead before conv)
  ushort* G0    = (ushort*)(base + 262144);           // alias lnTf region (bf16 [Mp][256])
  ushort* G1    = (ushort*)(base + 262144 + 9568256);
  ushort* X960  = (ushort*)(base + 22610944);         // [Mp][960] bf16
  ushort* P0    = (ushort*)(base + 58491904);         // [Mp][320] bf16 (layer input)
  ushort* P1    = (ushort*)(base + 70452224);         // rpt (conv A)
  ushort* P2    = (ushort*)(base + 82412544);         // attn out
  ushort* Wb    = (ushort*)(base + 94372864);         // 12 x [320][320] bf16
  ushort* Wpb   = (ushort*)(base + 96830464);         // 2 x [256][320] bf16
  const int WS = Kp*Kp;  // 102400

  // prologue (fp32)
  k_img_lnp<<<Bn, 256, 0, stream>>>(x2, Wimg, bimg, g2, be2, lnP);
  k_lnT<<<Bn, 1024, 0, stream>>>(x1, g1, be1, lnTf, (__hip_bfloat16*)P0);
  k_tp<<<Bn, 320, 0, stream>>>(lnP, lnTf, Wq_tp, Wk_tp, Wv_tp, Wv_pt, RTP, vpt);
  k_rptb<<<(Mn*Kp + 255)/256, 256, 0, stream>>>(lnTf, vpt, (__hip_bfloat16*)P1);

  Wptrs wp;
  for (int i = 0; i < 12; ++i) wp.p[i] = (const float*)d_in[14 + i];
  k_wcvt<<<(12*WS + 255)/256, 256, 0, stream>>>(wp, (__hip_bfloat16*)Wb);
  k_wpackb<<<(2*256*Kp + 255)/256, 256, 0, stream>>>(Wc1, Wc2, Wc3, Wc4, (__hip_bfloat16*)Wpb);

  dim3 gqkv(146*15, 1, 1), gproj(146*5, 1, 1), gconv(146*4, 1, 2), gat(Bn, Hn);
  for (int l = 0; l < 3; ++l) {
    const ushort* Wqkv = Wb + (size_t)l*4*WS;      // [960][320] stacked q,k,v
    const ushort* Wm   = Wb + ((size_t)l*4+3)*WS;  // [320][320]
    k_gemm3<<<gqkv, 256, 0, stream>>>(P0, P0, Wqkv, Wqkv, X960, X960, 15, 960);
    k_attn5<<<gat, 256, 0, stream>>>(X960, P2);
    k_gemm3<<<gproj, 256, 0, stream>>>(P2, P2, Wm, Wm, P0, P0, 5, 320);
  }
  // conv GEMMs: z0: G0 = rpt(P1) @ Wpb0.T ; z1: G1 = a3(P0) @ Wpb1.T
  k_gemm3<<<gconv, 256, 0, stream>>>(P1, P0, Wpb, Wpb + 256*Kp, G0, G1, 4, 256);
  k_convred2<<<dim3(Bn,4), 256, 0, stream>>>(G0, G1, bc1, bc2, bc3, bc4, out100);
  k_final<<<Bn, 320, 0, stream>>>(RTP, out100, Wlin, blin, Wlast, blast, (float*)d_out);
}

// Round 8
// 852.953 us; speedup vs baseline: 3.5726x; 1.0091x over previous
//
#include <hip/hip_runtime.h>
#include <hip/hip_bf16.h>
#include <math.h>

#define Bn 64
#define Tn 291
#define Dn 300
#define Hn 10
#define Mn (Bn*Tn)   // 18624
#define Mp 18688     // 146*128 padded rows
#define Kp 320       // padded K / activation pitch

typedef __bf16 bf16x8 __attribute__((ext_vector_type(8)));
typedef float f32x4 __attribute__((ext_vector_type(4)));

static __device__ __forceinline__ float leaky(float x){ return x >= 0.f ? x : 0.01f*x; }

template<int NT>
static __device__ __forceinline__ float blockSum(float v, float* red){
  __syncthreads();
  int lane = threadIdx.x & 63, wid = threadIdx.x >> 6;
  #pragma unroll
  for (int o = 32; o > 0; o >>= 1) v += __shfl_down(v, o, 64);
  if (lane == 0) red[wid] = v;
  __syncthreads();
  if (threadIdx.x == 0) {
    float s = red[0];
    #pragma unroll
    for (int w = 1; w < NT/64; ++w) s += red[w];
    red[0] = s;
  }
  __syncthreads();
  return red[0];
}

template<int NT>
static __device__ __forceinline__ float blockMax(float v, float* red){
  __syncthreads();
  int lane = threadIdx.x & 63, wid = threadIdx.x >> 6;
  #pragma unroll
  for (int o = 32; o > 0; o >>= 1) v = fmaxf(v, __shfl_down(v, o, 64));
  if (lane == 0) red[wid] = v;
  __syncthreads();
  if (threadIdx.x == 0) {
    float s = red[0];
    #pragma unroll
    for (int w = 1; w < NT/64; ++w) s = fmaxf(s, red[w]);
    red[0] = s;
  }
  __syncthreads();
  return red[0];
}

// ---- image branch ----
__global__ __launch_bounds__(256)
void k_img_lnp(const float* __restrict__ x2, const float* __restrict__ Wimg,
               const float* __restrict__ bimg, const float* __restrict__ g2,
               const float* __restrict__ be2, float* __restrict__ lnP)
{
  int b = blockIdx.x, tid = threadIdx.x;
  __shared__ float sx[1000];
  __shared__ float sy[300];
  __shared__ float red[4];
  for (int i = tid; i < 1000; i += 256) sx[i] = x2[b*1000 + i];
  __syncthreads();
  for (int j = tid; j < 300; j += 256) {
    const float* w = Wimg + j*1000;
    float a = 0.f;
    for (int i = 0; i < 1000; ++i) a += sx[i]*w[i];
    sy[j] = leaky(a + bimg[j]);
  }
  __syncthreads();
  float s = 0.f, ss = 0.f;
  for (int j = tid; j < 300; j += 256) { float v = sy[j]; s += v; ss += v*v; }
  float tot  = blockSum<256>(s, red);
  float tot2 = blockSum<256>(ss, red);
  float mu   = tot * (1.f/300.f);
  float var  = tot2 * (1.f/300.f) - mu*mu;
  float rstd = rsqrtf(var + 1e-5f);
  for (int j = tid; j < 300; j += 256)
    lnP[b*300 + j] = (sy[j]-mu)*rstd*g2[j] + be2[j];
}

// ---- lnT: LayerNorm over (291,300); fp32 (pitch 300) + bf16 (pitch 320, zero-padded) ----
__global__ __launch_bounds__(1024)
void k_lnT(const float* __restrict__ x1, const float* __restrict__ g1,
           const float* __restrict__ be1, float* __restrict__ outf,
           __hip_bfloat16* __restrict__ outb)
{
  int b = blockIdx.x, tid = threadIdx.x;
  __shared__ float red[16];
  const float4* xb = (const float4*)(x1 + (size_t)b*87300);
  const float4* g4 = (const float4*)g1;
  const float4* b4 = (const float4*)be1;
  float4* o4 = (float4*)(outf + (size_t)b*87300);
  float s = 0.f, ss = 0.f;
  for (int i = tid; i < 21825; i += 1024) {
    float4 v = xb[i];
    s  += v.x+v.y+v.z+v.w;
    ss += v.x*v.x+v.y*v.y+v.z*v.z+v.w*v.w;
  }
  float tot  = blockSum<1024>(s, red);
  float tot2 = blockSum<1024>(ss, red);
  float mu   = tot / 87300.f;
  float var  = tot2 / 87300.f - mu*mu;
  float rstd = rsqrtf(var + 1e-5f);
  for (int i = tid; i < 21825; i += 1024) {
    float4 v = xb[i], g = g4[i], be = b4[i], o;
    o.x = (v.x-mu)*rstd*g.x + be.x;
    o.y = (v.y-mu)*rstd*g.y + be.y;
    o.z = (v.z-mu)*rstd*g.z + be.z;
    o.w = (v.w-mu)*rstd*g.w + be.w;
    o4[i] = o;
  }
  const float* xs = x1 + (size_t)b*87300;
  for (int e = tid; e < Tn*Dn; e += 1024) {
    int t = e/300;
    float x = xs[e];
    outb[(size_t)(b*Tn+t)*Kp + (e - t*300)] = __float2bfloat16((x-mu)*rstd*g1[e] + be1[e]);
  }
  for (int e = tid; e < Tn*20; e += 1024) {
    int t = e/20, d = 300 + e%20;
    outb[(size_t)(b*Tn+t)*Kp + d] = __float2bfloat16(0.f);
  }
}

// ---- T->P cross attention (single query) + v for P->T branch ----
__global__ __launch_bounds__(320)
void k_tp(const float* __restrict__ lnP, const float* __restrict__ lnT,
          const float* __restrict__ Wq, const float* __restrict__ Wk,
          const float* __restrict__ Wv, const float* __restrict__ Wvpt,
          float* __restrict__ RTP, float* __restrict__ vpt)
{
  int b = blockIdx.x, tid = threadIdx.x;
  __shared__ float sP[300], sQ[300], sM[300], sA[291], sW[300], red[5];
  if (tid < 300) sP[tid] = lnP[b*300 + tid];
  __syncthreads();
  if (tid < 300) {
    const float* w = Wq + tid*300;
    float a = 0.f;
    for (int i = 0; i < 300; ++i) a += sP[i]*w[i];
    sQ[tid] = a;
  }
  __syncthreads();
  if (tid < 300) {
    float a = 0.f;
    for (int j = 0; j < 300; ++j) a += sQ[j]*Wk[j*300 + tid];
    sM[tid] = a;
  }
  __syncthreads();
  float sc = -1e30f;
  if (tid < 291) {
    const float* r = lnT + ((size_t)b*Tn + tid)*300;
    float a = 0.f;
    for (int i = 0; i < 300; ++i) a += r[i]*sM[i];
    sc = a;
  }
  float mx  = blockMax<320>(sc, red);
  float e   = (tid < 291) ? __expf(sc - mx) : 0.f;
  float den = blockSum<320>(e, red);
  if (tid < 291) sA[tid] = e;
  __syncthreads();
  if (tid < 300) {
    float a = 0.f;
    for (int t = 0; t < 291; ++t) a += sA[t]*lnT[((size_t)b*Tn + t)*300 + tid];
    sW[tid] = a / den;
  }
  __syncthreads();
  if (tid < 300) {
    const float* w = Wv + tid*300;
    float a = 0.f;
    for (int i = 0; i < 300; ++i) a += sW[i]*w[i];
    RTP[b*300 + tid] = a + sP[tid];
    const float* w2 = Wvpt + tid*300;
    float a2 = 0.f;
    for (int i = 0; i < 300; ++i) a2 += sP[i]*w2[i];
    vpt[b*300 + tid] = a2;
  }
}

// ---- rpt = lnT + vpt (broadcast over t), bf16 pitch-320 zero-padded ----
__global__ __launch_bounds__(256)
void k_rptb(const float* __restrict__ lnT, const float* __restrict__ vpt,
            __hip_bfloat16* __restrict__ out)
{
  int idx = blockIdx.x*256 + threadIdx.x;
  if (idx >= Mn*Kp) return;
  int m = idx / Kp, d = idx - m*Kp;
  int b = m / Tn;
  float v = (d < 300) ? lnT[(size_t)m*300 + d] + vpt[b*300 + d] : 0.f;
  out[idx] = __float2bfloat16(v);
}

struct Wptrs { const float* p[12]; };

// ---- build padded QKV weights: Wpad[l][1024][320].
//      row cc = hh*32+j; hh<10: Q head hh, 10..19: K, 20..29: V, 30/31: zero; j>=30 zero. ----
__global__ __launch_bounds__(256)
void k_wqkv(Wptrs wp, __hip_bfloat16* __restrict__ out)
{
  int idx = blockIdx.x*256 + threadIdx.x;
  if (idx >= 3*1024*Kp) return;
  int l = idx / (1024*Kp);
  int rem = idx - l*(1024*Kp);
  int rowp = rem / Kp, c = rem - rowp*Kp;
  int hh = rowp >> 5, j = rowp & 31;
  float v = 0.f;
  if (j < 30 && c < 300 && hh < 30) {
    int g = hh/10;
    v = wp.p[l*3 + g][((hh - g*10)*30 + j)*300 + c];
  }
  out[idx] = __float2bfloat16(v);
}

// ---- convert proj weights fp32[300][300] -> bf16[320][320] zero-padded ----
__global__ __launch_bounds__(256)
void k_wcvt(Wptrs wp, __hip_bfloat16* __restrict__ out, int nmat)
{
  int idx = blockIdx.x*256 + threadIdx.x;
  if (idx >= nmat*Kp*Kp) return;
  int mat = idx / (Kp*Kp);
  int rem = idx - mat*(Kp*Kp);
  int r = rem / Kp, c = rem - r*Kp;
  float v = (r < 300 && c < 300) ? wp.p[mat][r*300 + c] : 0.f;
  out[idx] = __float2bfloat16(v);
}

// ---- pack conv weights -> bf16 [2][256][320] zero-padded ----
__global__ __launch_bounds__(256)
void k_wpackb(const float* __restrict__ Wc1, const float* __restrict__ Wc2,
              const float* __restrict__ Wc3, const float* __restrict__ Wc4,
              __hip_bfloat16* __restrict__ out)
{
  int idx = blockIdx.x*256 + threadIdx.x;
  if (idx >= 2*256*Kp) return;
  int c  = idx % Kp;
  int rc = idx / Kp;
  int ch = rc / 256;
  int r  = rc % 256;
  float v = 0.f;
  if (r < 250 && c < 300) {
    const float* W; int kh, ro;
    if      (r < 25)  { W = Wc1; kh = 1; ro = r;      }
    else if (r < 75)  { W = Wc2; kh = 2; ro = r - 25; }
    else if (r < 150) { W = Wc3; kh = 3; ro = r - 75; }
    else              { W = Wc4; kh = 4; ro = r - 150;}
    int o = ro/kh, dh = ro%kh;
    v = W[((o*2 + ch)*kh + dh)*300 + c];
  }
  out[idx] = __float2bfloat16(v);
}

// ---- MFMA GEMM: C[m,n] = sum_k A[m,k]*W[n,k], K=320. 128x64 tile, 4 waves,
//      double-buffered LDS + XOR swizzle, bijective XCD-chunk swizzle.
//      PANEL: C stored as [n-panel][Mp][64] -> each block writes contiguous 16KB spans. ----
template<bool PANEL>
__global__ __launch_bounds__(256)
void k_gemm3(const ushort* __restrict__ A0, const ushort* __restrict__ A1,
             const ushort* __restrict__ W0, const ushort* __restrict__ W1,
             ushort* __restrict__ C0, ushort* __restrict__ C1,
             int nn, int cpitch)
{
  const ushort* A = blockIdx.z ? A1 : A0;
  const ushort* W = blockIdx.z ? W1 : W0;
  ushort*       C = blockIdx.z ? C1 : C0;
  int total = gridDim.x;
  int bid = blockIdx.x;
  int q = total >> 3, r = total & 7;
  int xcd = bid & 7, idx = bid >> 3;
  int wgid = (xcd < r ? xcd*(q+1) : r*(q+1) + (xcd-r)*q) + idx;
  int m0 = (wgid / nn) * 128, n0 = (wgid % nn) * 64;

  __shared__ alignas(16) ushort As[2][128*64];
  __shared__ alignas(16) ushort Bs[2][64*64];
  int tid = threadIdx.x;
  int lane = tid & 63, w = tid >> 6, wr = w >> 1, wc = w & 1;
  int lm = lane & 15, lk = lane >> 4;
  f32x4 acc[4][2] = {};
  uint4 ra[4], rw[2];

  auto loadregs = [&](int kt){
    #pragma unroll
    for (int u = 0; u < 4; ++u) {
      int s = tid + u*256; int row = s >> 3, kg = s & 7;
      ra[u] = *(const uint4*)(A + (size_t)(m0+row)*Kp + kt*64 + kg*8);
    }
    #pragma unroll
    for (int u = 0; u < 2; ++u) {
      int s = tid + u*256; int row = s >> 3, kg = s & 7;
      rw[u] = *(const uint4*)(W + (size_t)(n0+row)*Kp + kt*64 + kg*8);
    }
  };
  auto writeLDS = [&](int buf){
    #pragma unroll
    for (int u = 0; u < 4; ++u) {
      int s = tid + u*256; int row = s >> 3, kg = s & 7;
      *(uint4*)&As[buf][row*64 + ((kg ^ (row&7)) << 3)] = ra[u];
    }
    #pragma unroll
    for (int u = 0; u < 2; ++u) {
      int s = tid + u*256; int row = s >> 3, kg = s & 7;
      *(uint4*)&Bs[buf][row*64 + ((kg ^ (row&7)) << 3)] = rw[u];
    }
  };
  auto compute = [&](int buf){
    #pragma unroll
    for (int s = 0; s < 2; ++s) {
      bf16x8 af[4], bfr[2];
      int kg = s*4 + lk;
      #pragma unroll
      for (int mf = 0; mf < 4; ++mf) {
        int rr = wr*64 + mf*16 + lm;
        af[mf] = *(const bf16x8*)&As[buf][rr*64 + ((kg ^ (rr&7)) << 3)];
      }
      #pragma unroll
      for (int nf = 0; nf < 2; ++nf) {
        int rr = wc*32 + nf*16 + lm;
        bfr[nf] = *(const bf16x8*)&Bs[buf][rr*64 + ((kg ^ (rr&7)) << 3)];
      }
      #pragma unroll
      for (int mf = 0; mf < 4; ++mf)
        #pragma unroll
        for (int nf = 0; nf < 2; ++nf)
          acc[mf][nf] = __builtin_amdgcn_mfma_f32_16x16x32_bf16(af[mf], bfr[nf], acc[mf][nf], 0, 0, 0);
    }
  };

  loadregs(0); writeLDS(0);
  __syncthreads();
  #pragma unroll 1
  for (int kt = 0; kt < 5; ++kt) {
    if (kt < 4) loadregs(kt+1);
    compute(kt & 1);
    if (kt < 4) {
      __syncthreads();
      writeLDS((kt+1) & 1);
      __syncthreads();
    }
  }
  // acc -> LDS transpose (reuse As, 128x72 ushort) -> coalesced uint4 stores
  __syncthreads();
  ushort* T = &As[0][0];
  #pragma unroll
  for (int mf = 0; mf < 4; ++mf)
    #pragma unroll
    for (int nf = 0; nf < 2; ++nf)
      #pragma unroll
      for (int i = 0; i < 4; ++i) {
        int rr = wr*64 + mf*16 + lk*4 + i;
        int cc = wc*32 + nf*16 + lm;
        __hip_bfloat16 t = __float2bfloat16(acc[mf][nf][i]);
        T[rr*72 + cc] = *(ushort*)&t;
      }
  __syncthreads();
  #pragma unroll
  for (int u = 0; u < 4; ++u) {
    int s = tid + u*256; int row = s >> 3, g = s & 7;
    uint4 v = *(const uint4*)&T[row*72 + g*8];
    if (PANEL)
      *(uint4*)(C + ((size_t)(n0 >> 6)*Mp + m0 + row)*64 + g*8) = v;
    else
      *(uint4*)(C + (size_t)(m0+row)*cpitch + n0 + g*8) = v;
  }
}

// ---- MFMA flash attention. Xp = panel layout [16][Mp][64]: Q panels 0..4 (head h at
//      panel h/2, off (h&1)*32), K panels 5..9, V panels 10..14. Pad cols are zero.
//      O written row-major [Mp][320] at cols h*30..+30. ----
__global__ __launch_bounds__(256)
void k_attn6(const ushort* __restrict__ Xp, ushort* __restrict__ O)
{
  int b = blockIdx.x, h = blockIdx.y, tid = threadIdx.x;
  __shared__ alignas(16) ushort Ks[320*40];   // K rows, pitch 40
  __shared__ alignas(16) ushort Vt[32*328];   // V^T rows d, pitch 328
  __shared__ alignas(16) ushort Ps[64*168];   // P rows q (half-j), pitch 168
  const size_t rb = (size_t)b*Tn;
  const int Pq = h >> 1, off = (h & 1)*32;
  const int hq = h*30;
  for (int i = tid; i < 320*16; i += 256) {   // K staging (pad cols 30/31 zero from GEMM)
    int r = i >> 4, c2 = i & 15;
    uint v = (r < Tn) ? *(const uint*)(Xp + ((size_t)(5+Pq)*Mp + rb + r)*64 + off + 2*c2) : 0u;
    *(uint*)&Ks[r*40 + 2*c2] = v;
  }
  for (int i = tid; i < 320*16; i += 256) {   // V staging transposed
    int j = i >> 4, c2 = i & 15;
    uint v = (j < Tn) ? *(const uint*)(Xp + ((size_t)(10+Pq)*Mp + rb + j)*64 + off + 2*c2) : 0u;
    Vt[(2*c2)*328 + j]   = (ushort)(v & 0xffffu);
    Vt[(2*c2+1)*328 + j] = (ushort)(v >> 16);
  }
  __syncthreads();
  int lane = tid & 63, w = tid >> 6;
  int lm = lane & 15, lk = lane >> 4;
  int qloc = w*16 + lm;
  const float scale = 0.31622776601683794f;   // 1/sqrt(H)
  #pragma unroll 1
  for (int qt = 0; qt < 5; ++qt) {
    int qrow = qt*64 + w*16 + lm;             // may exceed Tn; masked at store
    union { uint u[4]; bf16x8 v; } qq;
    {
      const uint* qp = (const uint*)(Xp + ((size_t)Pq*Mp + rb + qrow)*64 + off + lk*8);
      qq.u[0]=qp[0]; qq.u[1]=qp[1]; qq.u[2]=qp[2]; qq.u[3]=qp[3];
    }
    bf16x8 qf = qq.v;
    float rsum = 0.f;
    f32x4 oacc[2] = {};
    #pragma unroll 1
    for (int jh = 0; jh < 2; ++jh) {
      #pragma unroll
      for (int jtl = 0; jtl < 10; ++jtl) {
        int jt = jh*10 + jtl;
        bf16x8 kf = *(const bf16x8*)&Ks[(jt*16+lm)*40 + lk*8];
        f32x4 s = {};
        s = __builtin_amdgcn_mfma_f32_16x16x32_bf16(kf, qf, s, 0, 0, 0);
        union { ushort u[4]; uint2 v2; } pk;
        #pragma unroll
        for (int i2 = 0; i2 < 4; ++i2) {
          int j = jt*16 + lk*4 + i2;
          float p = (j < Tn) ? __expf(s[i2]*scale) : 0.f;
          rsum += p;
          __hip_bfloat16 t = __float2bfloat16(p);
          pk.u[i2] = *(ushort*)&t;
        }
        *(uint2*)&Ps[qloc*168 + jtl*16 + lk*4] = pk.v2;
      }
      #pragma unroll
      for (int ktl = 0; ktl < 5; ++ktl) {
        bf16x8 pf = *(const bf16x8*)&Ps[qloc*168 + ktl*32 + lk*8];
        int jb = jh*160 + ktl*32 + lk*8;
        #pragma unroll
        for (int nf = 0; nf < 2; ++nf) {
          bf16x8 vf = *(const bf16x8*)&Vt[(nf*16+lm)*328 + jb];
          oacc[nf] = __builtin_amdgcn_mfma_f32_16x16x32_bf16(pf, vf, oacc[nf], 0, 0, 0);
        }
      }
    }
    rsum += __shfl_xor(rsum, 16, 64);
    rsum += __shfl_xor(rsum, 32, 64);
    float inv[4];
    #pragma unroll
    for (int i2 = 0; i2 < 4; ++i2) inv[i2] = 1.f / __shfl(rsum, lk*4 + i2, 64);
    #pragma unroll
    for (int nf = 0; nf < 2; ++nf) {
      int d = nf*16 + lm;
      if (d < 30) {
        #pragma unroll
        for (int i2 = 0; i2 < 4; ++i2) {
          int qrw = qt*64 + w*16 + lk*4 + i2;
          if (qrw < Tn) {
            __hip_bfloat16 t = __float2bfloat16(oacc[nf][i2]*inv[i2]);
            O[(rb + qrw)*Kp + hq + d] = *(ushort*)&t;
          }
        }
      }
    }
  }
}

// ---- conv head reduce: G0,G1 bf16 pitch 256 ----
__global__ __launch_bounds__(256)
void k_convred2(const ushort* __restrict__ G0, const ushort* __restrict__ G1,
                const float* __restrict__ bc1, const float* __restrict__ bc2,
                const float* __restrict__ bc3, const float* __restrict__ bc4,
                float* __restrict__ out100)
{
  int b = blockIdx.x, head = blockIdx.y;
  int kh  = head + 1;
  int off = (head == 0) ? 0 : (head == 1) ? 25 : (head == 2) ? 75 : 150;
  const float* bc = (head == 0) ? bc1 : (head == 1) ? bc2 : (head == 2) ? bc3 : bc4;
  int ncol = 25*kh;
  int ncp  = ncol | 1;
  int L = Tn - kh + 1;
  __shared__ float S[67*101];
  int tid = threadIdx.x, lane = tid & 63;
  float mx[7];
  #pragma unroll
  for (int u = 0; u < 7; ++u) mx[u] = -1e30f;
  for (int l0 = 0; l0 < L; l0 += 64) {
    int nrows = min(64 + kh - 1, Tn - l0);
    __syncthreads();
    for (int i = tid; i < nrows*ncol; i += 256) {
      int r = i / ncol, c = i % ncol;
      size_t g = (size_t)(b*Tn + l0 + r)*256 + off + c;
      __hip_bfloat16 a = *(const __hip_bfloat16*)&G0[g];
      __hip_bfloat16 d = *(const __hip_bfloat16*)&G1[g];
      S[r*ncp + c] = __bfloat162float(a) + __bfloat162float(d);
    }
    __syncthreads();
    int lmax = min(64, L - l0);
    #pragma unroll
    for (int u = 0; u < 7; ++u) {
      int o = (tid >> 6) + u*4;
      int dl = lane;
      if (o < 25 && dl < lmax) {
        float s = bc[o];
        for (int dh = 0; dh < kh; ++dh)
          s += S[(dl+dh)*ncp + o*kh + dh];
        mx[u] = fmaxf(mx[u], leaky(s));
      }
    }
  }
  #pragma unroll
  for (int u = 0; u < 7; ++u) {
    float v = mx[u];
    #pragma unroll
    for (int ofs = 32; ofs > 0; ofs >>= 1) v = fmaxf(v, __shfl_down(v, ofs, 64));
    int o = (tid >> 6) + u*4;
    if (lane == 0 && o < 25)
      out100[b*100 + head*25 + o] = v;
  }
}

// ---- final head ----
__global__ __launch_bounds__(320)
void k_final(const float* __restrict__ RTP, const float* __restrict__ out100,
             const float* __restrict__ Wlin, const float* __restrict__ blin,
             const float* __restrict__ Wlast, const float* __restrict__ blast,
             float* __restrict__ Y)
{
  int b = blockIdx.x, tid = threadIdx.x;
  __shared__ float cat[600];
  __shared__ float s100[100];
  __shared__ float red[5];
  if (tid < 100) s100[tid] = out100[b*100 + tid];
  if (tid < 300) cat[tid] = RTP[b*300 + tid];
  __syncthreads();
  if (tid < 300) {
    const float* w = Wlin + tid*100;
    float a = blin[tid];
    for (int j = 0; j < 100; ++j) a += s100[j]*w[j];
    cat[300 + tid] = leaky(a);
  }
  __syncthreads();
  for (int c = 0; c < 2; ++c) {
    float a = 0.f;
    for (int i = tid; i < 600; i += 320) a += cat[i]*Wlast[c*600 + i];
    a = blockSum<320>(a, red);
    if (tid == 0) Y[b*2 + c] = a + blast[c];
  }
}

extern "C" void kernel_launch(void* const* d_in, const int* in_sizes, int n_in,
                              void* d_out, int out_size, void* d_ws, size_t ws_size,
                              hipStream_t stream)
{
  (void)in_sizes; (void)n_in; (void)out_size; (void)ws_size;
  const float* x1    = (const float*)d_in[0];
  const float* x2    = (const float*)d_in[1];
  const float* Wimg  = (const float*)d_in[2];
  const float* bimg  = (const float*)d_in[3];
  const float* g1    = (const float*)d_in[4];
  const float* be1   = (const float*)d_in[5];
  const float* g2    = (const float*)d_in[6];
  const float* be2   = (const float*)d_in[7];
  const float* Wq_tp = (const float*)d_in[8];
  const float* Wk_tp = (const float*)d_in[9];
  const float* Wv_tp = (const float*)d_in[10];
  const float* Wv_pt = (const float*)d_in[13];   // Wq_pt/Wk_pt dead (softmax over size-1)
  const float* Wc1 = (const float*)d_in[26];
  const float* Wc2 = (const float*)d_in[27];
  const float* Wc3 = (const float*)d_in[28];
  const float* Wc4 = (const float*)d_in[29];
  const float* bc1 = (const float*)d_in[30];
  const float* bc2 = (const float*)d_in[31];
  const float* bc3 = (const float*)d_in[32];
  const float* bc4 = (const float*)d_in[33];
  const float* Wlin  = (const float*)d_in[34];
  const float* blin  = (const float*)d_in[35];
  const float* Wlast = (const float*)d_in[36];
  const float* blast = (const float*)d_in[37];

  char* base = (char*)d_ws;
  float* lnP    = (float*)(base + 0);
  float* RTP    = (float*)(base + 76800);
  float* vpt    = (float*)(base + 153600);
  float* out100 = (float*)(base + 230400);
  // region 262144..38535168: union{ lnTf fp32 (prologue) | X1024 (layers) | G0,G1 (conv) }
  float*  lnTf  = (float*)(base + 262144);            // 22.35 MB, dead after k_rptb
  ushort* X1024 = (ushort*)(base + 262144);           // [16][Mp][64] bf16 = 38.27 MB
  ushort* G0    = (ushort*)(base + 262144);           // bf16 [Mp][256], written after X dead
  ushort* G1    = (ushort*)(base + 262144 + 9568256);
  ushort* P0    = (ushort*)(base + 38535168);         // [Mp][320] bf16 (layer input)
  ushort* P1    = (ushort*)(base + 50495488);         // rpt (conv A)
  ushort* P2    = (ushort*)(base + 62455808);         // attn out
  ushort* Wpad  = (ushort*)(base + 74416128);         // 3 x [1024][320] bf16
  ushort* Wm    = (ushort*)(base + 76382208);         // 3 x [320][320] bf16
  ushort* Wpb   = (ushort*)(base + 76996608);         // 2 x [256][320] bf16
  const int WS = Kp*Kp;  // 102400

  // prologue (fp32)
  k_img_lnp<<<Bn, 256, 0, stream>>>(x2, Wimg, bimg, g2, be2, lnP);
  k_lnT<<<Bn, 1024, 0, stream>>>(x1, g1, be1, lnTf, (__hip_bfloat16*)P0);
  k_tp<<<Bn, 320, 0, stream>>>(lnP, lnTf, Wq_tp, Wk_tp, Wv_tp, Wv_pt, RTP, vpt);
  k_rptb<<<(Mn*Kp + 255)/256, 256, 0, stream>>>(lnTf, vpt, (__hip_bfloat16*)P1);

  // weights: padded QKV stacks + proj + conv
  Wptrs wq; // q,k,v per layer
  wq.p[0]=(const float*)d_in[14]; wq.p[1]=(const float*)d_in[15]; wq.p[2]=(const float*)d_in[16];
  wq.p[3]=(const float*)d_in[18]; wq.p[4]=(const float*)d_in[19]; wq.p[5]=(const float*)d_in[20];
  wq.p[6]=(const float*)d_in[22]; wq.p[7]=(const float*)d_in[23]; wq.p[8]=(const float*)d_in[24];
  k_wqkv<<<(3*1024*Kp + 255)/256, 256, 0, stream>>>(wq, (__hip_bfloat16*)Wpad);
  Wptrs wm;
  wm.p[0]=(const float*)d_in[17]; wm.p[1]=(const float*)d_in[21]; wm.p[2]=(const float*)d_in[25];
  k_wcvt<<<(3*WS + 255)/256, 256, 0, stream>>>(wm, (__hip_bfloat16*)Wm, 3);
  k_wpackb<<<(2*256*Kp + 255)/256, 256, 0, stream>>>(Wc1, Wc2, Wc3, Wc4, (__hip_bfloat16*)Wpb);

  dim3 gqkv(146*16, 1, 1), gproj(146*5, 1, 1), gconv(146*4, 1, 2), gat(Bn, Hn);
  for (int l = 0; l < 3; ++l) {
    const ushort* Wq3 = Wpad + (size_t)l*1024*Kp;   // [1024][320] padded q|k|v
    const ushort* Wm3 = Wm + (size_t)l*WS;          // [320][320]
    k_gemm3<true ><<<gqkv, 256, 0, stream>>>(P0, P0, Wq3, Wq3, X1024, X1024, 16, 0);
    k_attn6<<<gat, 256, 0, stream>>>(X1024, P2);
    k_gemm3<false><<<gproj, 256, 0, stream>>>(P2, P2, Wm3, Wm3, P0, P0, 5, 320);
  }
  // conv GEMMs: G0 = rpt(P1) @ Wpb0.T ; G1 = a3(P0) @ Wpb1.T  (row-major pitch 256)
  k_gemm3<false><<<gconv, 256, 0, stream>>>(P1, P0, Wpb, Wpb + 256*Kp, G0, G1, 4, 256);
  k_convred2<<<dim3(Bn,4), 256, 0, stream>>>(G0, G1, bc1, bc2, bc3, bc4, out100);
  k_final<<<Bn, 320, 0, stream>>>(RTP, out100, Wlin, blin, Wlast, blast, (float*)d_out);
}

// Round 9
// 692.431 us; speedup vs baseline: 4.4008x; 1.2318x over previous
//
#include <hip/hip_runtime.h>
#include <hip/hip_bf16.h>
#include <math.h>

#define Bn 64
#define Tn 291
#define Dn 300
#define Hn 10
#define Mn (Bn*Tn)   // 18624
#define Mp 18688     // 292*64 padded rows
#define Kp 320       // padded K

typedef __bf16 bf16x8 __attribute__((ext_vector_type(8)));
typedef float f32x4 __attribute__((ext_vector_type(4)));

static __device__ __forceinline__ float leaky(float x){ return x >= 0.f ? x : 0.01f*x; }

// panel-layout address: activation buffers are [ncolpanels][Mp][64] bf16
static __device__ __forceinline__ size_t pidx(int m, int c){
  return ((size_t)(c >> 6)*Mp + m)*64 + (c & 63);
}

template<int NT>
static __device__ __forceinline__ float blockSum(float v, float* red){
  __syncthreads();
  int lane = threadIdx.x & 63, wid = threadIdx.x >> 6;
  #pragma unroll
  for (int o = 32; o > 0; o >>= 1) v += __shfl_down(v, o, 64);
  if (lane == 0) red[wid] = v;
  __syncthreads();
  if (threadIdx.x == 0) {
    float s = red[0];
    #pragma unroll
    for (int w = 1; w < NT/64; ++w) s += red[w];
    red[0] = s;
  }
  __syncthreads();
  return red[0];
}

template<int NT>
static __device__ __forceinline__ float blockMax(float v, float* red){
  __syncthreads();
  int lane = threadIdx.x & 63, wid = threadIdx.x >> 6;
  #pragma unroll
  for (int o = 32; o > 0; o >>= 1) v = fmaxf(v, __shfl_down(v, o, 64));
  if (lane == 0) red[wid] = v;
  __syncthreads();
  if (threadIdx.x == 0) {
    float s = red[0];
    #pragma unroll
    for (int w = 1; w < NT/64; ++w) s = fmaxf(s, red[w]);
    red[0] = s;
  }
  __syncthreads();
  return red[0];
}

// ---- image branch ----
__global__ __launch_bounds__(256)
void k_img_lnp(const float* __restrict__ x2, const float* __restrict__ Wimg,
               const float* __restrict__ bimg, const float* __restrict__ g2,
               const float* __restrict__ be2, float* __restrict__ lnP)
{
  int b = blockIdx.x, tid = threadIdx.x;
  __shared__ float sx[1000];
  __shared__ float sy[300];
  __shared__ float red[4];
  for (int i = tid; i < 1000; i += 256) sx[i] = x2[b*1000 + i];
  __syncthreads();
  for (int j = tid; j < 300; j += 256) {
    const float* w = Wimg + j*1000;
    float a = 0.f;
    for (int i = 0; i < 1000; ++i) a += sx[i]*w[i];
    sy[j] = leaky(a + bimg[j]);
  }
  __syncthreads();
  float s = 0.f, ss = 0.f;
  for (int j = tid; j < 300; j += 256) { float v = sy[j]; s += v; ss += v*v; }
  float tot  = blockSum<256>(s, red);
  float tot2 = blockSum<256>(ss, red);
  float mu   = tot * (1.f/300.f);
  float var  = tot2 * (1.f/300.f) - mu*mu;
  float rstd = rsqrtf(var + 1e-5f);
  for (int j = tid; j < 300; j += 256)
    lnP[b*300 + j] = (sy[j]-mu)*rstd*g2[j] + be2[j];
}

// ---- lnT: LayerNorm over (291,300); fp32 (pitch 300) + bf16 panel layout ----
__global__ __launch_bounds__(1024)
void k_lnT(const float* __restrict__ x1, const float* __restrict__ g1,
           const float* __restrict__ be1, float* __restrict__ outf,
           __hip_bfloat16* __restrict__ outb)
{
  int b = blockIdx.x, tid = threadIdx.x;
  __shared__ float red[16];
  const float4* xb = (const float4*)(x1 + (size_t)b*87300);
  const float4* g4 = (const float4*)g1;
  const float4* b4 = (const float4*)be1;
  float4* o4 = (float4*)(outf + (size_t)b*87300);
  float s = 0.f, ss = 0.f;
  for (int i = tid; i < 21825; i += 1024) {
    float4 v = xb[i];
    s  += v.x+v.y+v.z+v.w;
    ss += v.x*v.x+v.y*v.y+v.z*v.z+v.w*v.w;
  }
  float tot  = blockSum<1024>(s, red);
  float tot2 = blockSum<1024>(ss, red);
  float mu   = tot / 87300.f;
  float var  = tot2 / 87300.f - mu*mu;
  float rstd = rsqrtf(var + 1e-5f);
  for (int i = tid; i < 21825; i += 1024) {
    float4 v = xb[i], g = g4[i], be = b4[i], o;
    o.x = (v.x-mu)*rstd*g.x + be.x;
    o.y = (v.y-mu)*rstd*g.y + be.y;
    o.z = (v.z-mu)*rstd*g.z + be.z;
    o.w = (v.w-mu)*rstd*g.w + be.w;
    o4[i] = o;
  }
  const float* xs = x1 + (size_t)b*87300;
  for (int e = tid; e < Tn*Dn; e += 1024) {
    int t = e/300, d = e - t*300;
    float x = xs[e];
    outb[pidx(b*Tn + t, d)] = __float2bfloat16((x-mu)*rstd*g1[e] + be1[e]);
  }
  for (int e = tid; e < Tn*20; e += 1024) {
    int t = e/20, d = 300 + e%20;
    outb[pidx(b*Tn + t, d)] = __float2bfloat16(0.f);
  }
}

// ---- T->P cross attention (single query) + v for P->T branch ----
__global__ __launch_bounds__(320)
void k_tp(const float* __restrict__ lnP, const float* __restrict__ lnT,
          const float* __restrict__ Wq, const float* __restrict__ Wk,
          const float* __restrict__ Wv, const float* __restrict__ Wvpt,
          float* __restrict__ RTP, float* __restrict__ vpt)
{
  int b = blockIdx.x, tid = threadIdx.x;
  __shared__ float sP[300], sQ[300], sM[300], sA[291], sW[300], red[5];
  if (tid < 300) sP[tid] = lnP[b*300 + tid];
  __syncthreads();
  if (tid < 300) {
    const float* w = Wq + tid*300;
    float a = 0.f;
    for (int i = 0; i < 300; ++i) a += sP[i]*w[i];
    sQ[tid] = a;
  }
  __syncthreads();
  if (tid < 300) {
    float a = 0.f;
    for (int j = 0; j < 300; ++j) a += sQ[j]*Wk[j*300 + tid];
    sM[tid] = a;
  }
  __syncthreads();
  float sc = -1e30f;
  if (tid < 291) {
    const float* r = lnT + ((size_t)b*Tn + tid)*300;
    float a = 0.f;
    for (int i = 0; i < 300; ++i) a += r[i]*sM[i];
    sc = a;
  }
  float mx  = blockMax<320>(sc, red);
  float e   = (tid < 291) ? __expf(sc - mx) : 0.f;
  float den = blockSum<320>(e, red);
  if (tid < 291) sA[tid] = e;
  __syncthreads();
  if (tid < 300) {
    float a = 0.f;
    for (int t = 0; t < 291; ++t) a += sA[t]*lnT[((size_t)b*Tn + t)*300 + tid];
    sW[tid] = a / den;
  }
  __syncthreads();
  if (tid < 300) {
    const float* w = Wv + tid*300;
    float a = 0.f;
    for (int i = 0; i < 300; ++i) a += sW[i]*w[i];
    RTP[b*300 + tid] = a + sP[tid];
    const float* w2 = Wvpt + tid*300;
    float a2 = 0.f;
    for (int i = 0; i < 300; ++i) a2 += sP[i]*w2[i];
    vpt[b*300 + tid] = a2;
  }
}

// ---- rpt = lnT + vpt, bf16 panel layout, pad cols zeroed ----
__global__ __launch_bounds__(256)
void k_rptb(const float* __restrict__ lnT, const float* __restrict__ vpt,
            __hip_bfloat16* __restrict__ out)
{
  int idx = blockIdx.x*256 + threadIdx.x;
  if (idx >= Mn*Kp) return;
  int m = idx / Kp, d = idx - m*Kp;
  int b = m / Tn;
  float v = (d < 300) ? lnT[(size_t)m*300 + d] + vpt[b*300 + d] : 0.f;
  out[pidx(m, d)] = __float2bfloat16(v);
}

struct Wptrs { const float* p[12]; };

// ---- padded QKV weights: Wpad[l][1024][320]; row cc = hh*32+j (hh<10 Q, <20 K, <30 V) ----
__global__ __launch_bounds__(256)
void k_wqkv(Wptrs wp, __hip_bfloat16* __restrict__ out)
{
  int idx = blockIdx.x*256 + threadIdx.x;
  if (idx >= 3*1024*Kp) return;
  int l = idx / (1024*Kp);
  int rem = idx - l*(1024*Kp);
  int rowp = rem / Kp, c = rem - rowp*Kp;
  int hh = rowp >> 5, j = rowp & 31;
  float v = 0.f;
  if (j < 30 && c < 300 && hh < 30) {
    int g = hh/10;
    v = wp.p[l*3 + g][((hh - g*10)*30 + j)*300 + c];
  }
  out[idx] = __float2bfloat16(v);
}

// ---- proj weights fp32[300][300] -> bf16[320][320] zero-padded ----
__global__ __launch_bounds__(256)
void k_wcvt(Wptrs wp, __hip_bfloat16* __restrict__ out, int nmat)
{
  int idx = blockIdx.x*256 + threadIdx.x;
  if (idx >= nmat*Kp*Kp) return;
  int mat = idx / (Kp*Kp);
  int rem = idx - mat*(Kp*Kp);
  int r = rem / Kp, c = rem - r*Kp;
  float v = (r < 300 && c < 300) ? wp.p[mat][r*300 + c] : 0.f;
  out[idx] = __float2bfloat16(v);
}

// ---- conv weights -> bf16 [2][256][320] zero-padded ----
__global__ __launch_bounds__(256)
void k_wpackb(const float* __restrict__ Wc1, const float* __restrict__ Wc2,
              const float* __restrict__ Wc3, const float* __restrict__ Wc4,
              __hip_bfloat16* __restrict__ out)
{
  int idx = blockIdx.x*256 + threadIdx.x;
  if (idx >= 2*256*Kp) return;
  int c  = idx % Kp;
  int rc = idx / Kp;
  int ch = rc / 256;
  int r  = rc % 256;
  float v = 0.f;
  if (r < 250 && c < 300) {
    const float* W; int kh, ro;
    if      (r < 25)  { W = Wc1; kh = 1; ro = r;      }
    else if (r < 75)  { W = Wc2; kh = 2; ro = r - 25; }
    else if (r < 150) { W = Wc3; kh = 3; ro = r - 75; }
    else              { W = Wc4; kh = 4; ro = r - 150;}
    int o = ro/kh, dh = ro%kh;
    v = W[((o*2 + ch)*kh + dh)*300 + c];
  }
  out[idx] = __float2bfloat16(v);
}

// ---- GEMM v4: C[m,n] = sum_k A[m,k]*W[n,k], K=320. BM=64, A LDS-resident (one stage,
//      one barrier), then BARRIER-FREE per-wave loop over 64-col panels: B-fragments
//      register-prefetched from L2-resident W; sequential per-wave panel writes via
//      wave-private LDS transpose. A panel-layout in, C panel-layout out. 49KB LDS. ----
__global__ __launch_bounds__(256)
void k_gemm4(const ushort* __restrict__ A0, const ushort* __restrict__ A1,
             const ushort* __restrict__ W0, const ushort* __restrict__ W1,
             ushort* __restrict__ C0, ushort* __restrict__ C1,
             int pbase_z, int pcnt, int nptot)
{
  const ushort* A = blockIdx.z ? A1 : A0;
  const ushort* W = blockIdx.z ? W1 : W0;
  ushort*       C = blockIdx.z ? C1 : C0;
  int m0 = blockIdx.x * 64;
  __shared__ alignas(16) ushort As[64*320];    // swizzled, 40 KB
  __shared__ alignas(16) ushort Tb[4][16*72];  // wave-private transpose, 9.2 KB
  int tid = threadIdx.x, lane = tid & 63, w = tid >> 6;
  int lm = lane & 15, lk = lane >> 4;

  // stage A once: 64 rows x 320 cols (panel-layout source), XOR-swizzled
  #pragma unroll
  for (int u = 0; u < 10; ++u) {
    int s = u*256 + tid;           // [0,2560): row = s/40, kg = s%40 (8-col group)
    int row = s/40, kg = s%40;
    uint4 v = *(const uint4*)(A + ((size_t)(kg>>3)*Mp + m0 + row)*64 + (kg&7)*8);
    int kgs = (kg & ~7) | ((kg ^ row) & 7);
    *(uint4*)&As[row*320 + kgs*8] = v;
  }
  __syncthreads();

  int ps = blockIdx.z * pbase_z;
  int pe = min(ps + pcnt, nptot);
  for (int p = ps + w; p < pe; p += 4) {
    int n0 = p*64;
    f32x4 acc[4][4] = {};
    bf16x8 bcur[4], bnxt[4];
    #pragma unroll
    for (int nf = 0; nf < 4; ++nf)
      bcur[nf] = *(const bf16x8*)(W + (size_t)(n0 + nf*16 + lm)*Kp + lk*8);
    for (int ks = 0; ks < 10; ++ks) {
      if (ks < 9) {
        #pragma unroll
        for (int nf = 0; nf < 4; ++nf)
          bnxt[nf] = *(const bf16x8*)(W + (size_t)(n0 + nf*16 + lm)*Kp + (ks+1)*32 + lk*8);
      }
      bf16x8 af[4];
      #pragma unroll
      for (int mf = 0; mf < 4; ++mf) {
        int r = mf*16 + lm;
        int kg = ks*4 + lk;
        int kgs = (kg & ~7) | ((kg ^ r) & 7);
        af[mf] = *(const bf16x8*)&As[r*320 + kgs*8];
      }
      #pragma unroll
      for (int mf = 0; mf < 4; ++mf)
        #pragma unroll
        for (int nf = 0; nf < 4; ++nf)
          acc[mf][nf] = __builtin_amdgcn_mfma_f32_16x16x32_bf16(af[mf], bcur[nf], acc[mf][nf], 0, 0, 0);
      #pragma unroll
      for (int nf = 0; nf < 4; ++nf) bcur[nf] = bnxt[nf];
    }
    // store: per 16-row chunk, wave-private transpose then coalesced uint4 writes
    #pragma unroll
    for (int mf = 0; mf < 4; ++mf) {
      #pragma unroll
      for (int nf = 0; nf < 4; ++nf)
        #pragma unroll
        for (int i = 0; i < 4; ++i) {
          __hip_bfloat16 t = __float2bfloat16(acc[mf][nf][i]);
          Tb[w][(lk*4 + i)*72 + nf*16 + lm] = *(ushort*)&t;   // C[m=mf*16+lk*4+i][n=nf*16+lm]
        }
      // wave-local RAW on Tb[w]: compiler orders via lgkmcnt (same LDS object)
      #pragma unroll
      for (int u = 0; u < 2; ++u) {
        int s2 = u*64 + lane;       // [0,128): row = s2>>3, g = s2&7
        int row = s2 >> 3, g = s2 & 7;
        uint4 v = *(const uint4*)&Tb[w][row*72 + g*8];
        *(uint4*)(C + ((size_t)p*Mp + m0 + mf*16 + row)*64 + g*8) = v;
      }
    }
  }
}

// ---- MFMA flash attention. Xp = [16][Mp][64]: Q panels 0..4 (head h -> panel h>>1,
//      off (h&1)*32), K panels 5..9, V panels 10..14. Pad cols zero. O -> panel layout. ----
__global__ __launch_bounds__(256)
void k_attn6(const ushort* __restrict__ Xp, ushort* __restrict__ O)
{
  int b = blockIdx.x, h = blockIdx.y, tid = threadIdx.x;
  __shared__ alignas(16) ushort Ks[320*40];
  __shared__ alignas(16) ushort Vt[32*328];
  __shared__ alignas(16) ushort Ps[64*168];
  const size_t rb = (size_t)b*Tn;
  const int Pq = h >> 1, off = (h & 1)*32;
  const int hq = h*30;
  for (int i = tid; i < 320*16; i += 256) {
    int r = i >> 4, c2 = i & 15;
    uint v = (r < Tn) ? *(const uint*)(Xp + ((size_t)(5+Pq)*Mp + rb + r)*64 + off + 2*c2) : 0u;
    *(uint*)&Ks[r*40 + 2*c2] = v;
  }
  for (int i = tid; i < 320*16; i += 256) {
    int j = i >> 4, c2 = i & 15;
    uint v = (j < Tn) ? *(const uint*)(Xp + ((size_t)(10+Pq)*Mp + rb + j)*64 + off + 2*c2) : 0u;
    Vt[(2*c2)*328 + j]   = (ushort)(v & 0xffffu);
    Vt[(2*c2+1)*328 + j] = (ushort)(v >> 16);
  }
  __syncthreads();
  int lane = tid & 63, w = tid >> 6;
  int lm = lane & 15, lk = lane >> 4;
  int qloc = w*16 + lm;
  const float scale = 0.31622776601683794f;   // 1/sqrt(H)
  #pragma unroll 1
  for (int qt = 0; qt < 5; ++qt) {
    int qrow = qt*64 + w*16 + lm;             // may exceed Tn; masked at store
    union { uint u[4]; bf16x8 v; } qq;
    {
      const uint* qp = (const uint*)(Xp + ((size_t)Pq*Mp + rb + qrow)*64 + off + lk*8);
      qq.u[0]=qp[0]; qq.u[1]=qp[1]; qq.u[2]=qp[2]; qq.u[3]=qp[3];
    }
    bf16x8 qf = qq.v;
    float rsum = 0.f;
    f32x4 oacc[2] = {};
    #pragma unroll 1
    for (int jh = 0; jh < 2; ++jh) {
      #pragma unroll
      for (int jtl = 0; jtl < 10; ++jtl) {
        int jt = jh*10 + jtl;
        bf16x8 kf = *(const bf16x8*)&Ks[(jt*16+lm)*40 + lk*8];
        f32x4 s = {};
        s = __builtin_amdgcn_mfma_f32_16x16x32_bf16(kf, qf, s, 0, 0, 0);
        union { ushort u[4]; uint2 v2; } pk;
        #pragma unroll
        for (int i2 = 0; i2 < 4; ++i2) {
          int j = jt*16 + lk*4 + i2;
          float p = (j < Tn) ? __expf(s[i2]*scale) : 0.f;
          rsum += p;
          __hip_bfloat16 t = __float2bfloat16(p);
          pk.u[i2] = *(ushort*)&t;
        }
        *(uint2*)&Ps[qloc*168 + jtl*16 + lk*4] = pk.v2;
      }
      #pragma unroll
      for (int ktl = 0; ktl < 5; ++ktl) {
        bf16x8 pf = *(const bf16x8*)&Ps[qloc*168 + ktl*32 + lk*8];
        int jb = jh*160 + ktl*32 + lk*8;
        #pragma unroll
        for (int nf = 0; nf < 2; ++nf) {
          bf16x8 vf = *(const bf16x8*)&Vt[(nf*16+lm)*328 + jb];
          oacc[nf] = __builtin_amdgcn_mfma_f32_16x16x32_bf16(pf, vf, oacc[nf], 0, 0, 0);
        }
      }
    }
    rsum += __shfl_xor(rsum, 16, 64);
    rsum += __shfl_xor(rsum, 32, 64);
    float inv[4];
    #pragma unroll
    for (int i2 = 0; i2 < 4; ++i2) inv[i2] = 1.f / __shfl(rsum, lk*4 + i2, 64);
    #pragma unroll
    for (int nf = 0; nf < 2; ++nf) {
      int d = nf*16 + lm;
      if (d < 30) {
        #pragma unroll
        for (int i2 = 0; i2 < 4; ++i2) {
          int qrw = qt*64 + w*16 + lk*4 + i2;
          if (qrw < Tn) {
            __hip_bfloat16 t = __float2bfloat16(oacc[nf][i2]*inv[i2]);
            O[pidx(rb + qrw, hq + d)] = *(ushort*)&t;
          }
        }
      }
    }
  }
}

// ---- conv head reduce: G0,G1 bf16 panel layout [4][Mp][64] ----
__global__ __launch_bounds__(256)
void k_convred2(const ushort* __restrict__ G0, const ushort* __restrict__ G1,
                const float* __restrict__ bc1, const float* __restrict__ bc2,
                const float* __restrict__ bc3, const float* __restrict__ bc4,
                float* __restrict__ out100)
{
  int b = blockIdx.x, head = blockIdx.y;
  int kh  = head + 1;
  int off = (head == 0) ? 0 : (head == 1) ? 25 : (head == 2) ? 75 : 150;
  const float* bc = (head == 0) ? bc1 : (head == 1) ? bc2 : (head == 2) ? bc3 : bc4;
  int ncol = 25*kh;
  int ncp  = ncol | 1;
  int L = Tn - kh + 1;
  __shared__ float S[67*101];
  int tid = threadIdx.x, lane = tid & 63;
  float mx[7];
  #pragma unroll
  for (int u = 0; u < 7; ++u) mx[u] = -1e30f;
  for (int l0 = 0; l0 < L; l0 += 64) {
    int nrows = min(64 + kh - 1, Tn - l0);
    __syncthreads();
    for (int i = tid; i < nrows*ncol; i += 256) {
      int r = i / ncol, c = i % ncol;
      int col = off + c;
      size_t g = pidx(b*Tn + l0 + r, col);
      __hip_bfloat16 a = *(const __hip_bfloat16*)&G0[g];
      __hip_bfloat16 d = *(const __hip_bfloat16*)&G1[g];
      S[r*ncp + c] = __bfloat162float(a) + __bfloat162float(d);
    }
    __syncthreads();
    int lmax = min(64, L - l0);
    #pragma unroll
    for (int u = 0; u < 7; ++u) {
      int o = (tid >> 6) + u*4;
      int dl = lane;
      if (o < 25 && dl < lmax) {
        float s = bc[o];
        for (int dh = 0; dh < kh; ++dh)
          s += S[(dl+dh)*ncp + o*kh + dh];
        mx[u] = fmaxf(mx[u], leaky(s));
      }
    }
  }
  #pragma unroll
  for (int u = 0; u < 7; ++u) {
    float v = mx[u];
    #pragma unroll
    for (int ofs = 32; ofs > 0; ofs >>= 1) v = fmaxf(v, __shfl_down(v, ofs, 64));
    int o = (tid >> 6) + u*4;
    if (lane == 0 && o < 25)
      out100[b*100 + head*25 + o] = v;
  }
}

// ---- final head ----
__global__ __launch_bounds__(320)
void k_final(const float* __restrict__ RTP, const float* __restrict__ out100,
             const float* __restrict__ Wlin, const float* __restrict__ blin,
             const float* __restrict__ Wlast, const float* __restrict__ blast,
             float* __restrict__ Y)
{
  int b = blockIdx.x, tid = threadIdx.x;
  __shared__ float cat[600];
  __shared__ float s100[100];
  __shared__ float red[5];
  if (tid < 100) s100[tid] = out100[b*100 + tid];
  if (tid < 300) cat[tid] = RTP[b*300 + tid];
  __syncthreads();
  if (tid < 300) {
    const float* w = Wlin + tid*100;
    float a = blin[tid];
    for (int j = 0; j < 100; ++j) a += s100[j]*w[j];
    cat[300 + tid] = leaky(a);
  }
  __syncthreads();
  for (int c = 0; c < 2; ++c) {
    float a = 0.f;
    for (int i = tid; i < 600; i += 320) a += cat[i]*Wlast[c*600 + i];
    a = blockSum<320>(a, red);
    if (tid == 0) Y[b*2 + c] = a + blast[c];
  }
}

extern "C" void kernel_launch(void* const* d_in, const int* in_sizes, int n_in,
                              void* d_out, int out_size, void* d_ws, size_t ws_size,
                              hipStream_t stream)
{
  (void)in_sizes; (void)n_in; (void)out_size; (void)ws_size;
  const float* x1    = (const float*)d_in[0];
  const float* x2    = (const float*)d_in[1];
  const float* Wimg  = (const float*)d_in[2];
  const float* bimg  = (const float*)d_in[3];
  const float* g1    = (const float*)d_in[4];
  const float* be1   = (const float*)d_in[5];
  const float* g2    = (const float*)d_in[6];
  const float* be2   = (const float*)d_in[7];
  const float* Wq_tp = (const float*)d_in[8];
  const float* Wk_tp = (const float*)d_in[9];
  const float* Wv_tp = (const float*)d_in[10];
  const float* Wv_pt = (const float*)d_in[13];   // Wq_pt/Wk_pt dead (softmax over size-1)
  const float* Wc1 = (const float*)d_in[26];
  const float* Wc2 = (const float*)d_in[27];
  const float* Wc3 = (const float*)d_in[28];
  const float* Wc4 = (const float*)d_in[29];
  const float* bc1 = (const float*)d_in[30];
  const float* bc2 = (const float*)d_in[31];
  const float* bc3 = (const float*)d_in[32];
  const float* bc4 = (const float*)d_in[33];
  const float* Wlin  = (const float*)d_in[34];
  const float* blin  = (const float*)d_in[35];
  const float* Wlast = (const float*)d_in[36];
  const float* blast = (const float*)d_in[37];

  char* base = (char*)d_ws;
  float* lnP    = (float*)(base + 0);
  float* RTP    = (float*)(base + 76800);
  float* vpt    = (float*)(base + 153600);
  float* out100 = (float*)(base + 230400);
  // region 262144..38535168: union{ lnTf fp32 (prologue) | X1024 (layers) | G0,G1 (conv) }
  float*  lnTf  = (float*)(base + 262144);
  ushort* X1024 = (ushort*)(base + 262144);           // [16][Mp][64] bf16
  ushort* G0    = (ushort*)(base + 262144);           // [4][Mp][64] bf16, written after X dead
  ushort* G1    = (ushort*)(base + 262144 + 9568256);
  ushort* P0    = (ushort*)(base + 38535168);         // [5][Mp][64] (layer input)
  ushort* P1    = (ushort*)(base + 50495488);         // rpt (conv A)
  ushort* P2    = (ushort*)(base + 62455808);         // attn out
  ushort* Wpad  = (ushort*)(base + 74416128);         // 3 x [1024][320] bf16
  ushort* Wm    = (ushort*)(base + 76382208);         // 3 x [320][320] bf16
  ushort* Wpb   = (ushort*)(base + 76996608);         // 2 x [256][320] bf16
  const int WS = Kp*Kp;  // 102400

  // prologue (fp32)
  k_img_lnp<<<Bn, 256, 0, stream>>>(x2, Wimg, bimg, g2, be2, lnP);
  k_lnT<<<Bn, 1024, 0, stream>>>(x1, g1, be1, lnTf, (__hip_bfloat16*)P0);
  k_tp<<<Bn, 320, 0, stream>>>(lnP, lnTf, Wq_tp, Wk_tp, Wv_tp, Wv_pt, RTP, vpt);
  k_rptb<<<(Mn*Kp + 255)/256, 256, 0, stream>>>(lnTf, vpt, (__hip_bfloat16*)P1);

  Wptrs wq;
  wq.p[0]=(const float*)d_in[14]; wq.p[1]=(const float*)d_in[15]; wq.p[2]=(const float*)d_in[16];
  wq.p[3]=(const float*)d_in[18]; wq.p[4]=(const float*)d_in[19]; wq.p[5]=(const float*)d_in[20];
  wq.p[6]=(const float*)d_in[22]; wq.p[7]=(const float*)d_in[23]; wq.p[8]=(const float*)d_in[24];
  k_wqkv<<<(3*1024*Kp + 255)/256, 256, 0, stream>>>(wq, (__hip_bfloat16*)Wpad);
  Wptrs wm;
  wm.p[0]=(const float*)d_in[17]; wm.p[1]=(const float*)d_in[21]; wm.p[2]=(const float*)d_in[25];
  k_wcvt<<<(3*WS + 255)/256, 256, 0, stream>>>(wm, (__hip_bfloat16*)Wm, 3);
  k_wpackb<<<(2*256*Kp + 255)/256, 256, 0, stream>>>(Wc1, Wc2, Wc3, Wc4, (__hip_bfloat16*)Wpb);

  dim3 g2z(292, 1, 2), gat(Bn, Hn);
  for (int l = 0; l < 3; ++l) {
    const ushort* Wq3 = Wpad + (size_t)l*1024*Kp;   // [1024][320] padded q|k|v
    const ushort* Wm3 = Wm + (size_t)l*WS;          // [320][320]
    // QKV: z splits 16 panels into [0,8) and [8,16)
    k_gemm4<<<g2z, 256, 0, stream>>>(P0, P0, Wq3, Wq3, X1024, X1024, 8, 8, 16);
    k_attn6<<<gat, 256, 0, stream>>>(X1024, P2);
    // proj: z splits 5 panels into [0,3) and [3,5)
    k_gemm4<<<g2z, 256, 0, stream>>>(P2, P2, Wm3, Wm3, P0, P0, 3, 3, 5);
  }
  // conv: z selects (A,W,C); both z cover panels [0,4)
  k_gemm4<<<g2z, 256, 0, stream>>>(P1, P0, Wpb, Wpb + 256*Kp, G0, G1, 0, 4, 4);
  k_convred2<<<dim3(Bn,4), 256, 0, stream>>>(G0, G1, bc1, bc2, bc3, bc4, out100);
  k_final<<<Bn, 320, 0, stream>>>(RTP, out100, Wlin, blin, Wlast, blast, (float*)d_out);
}